// Round 1
// baseline (1515.836 us; speedup 1.0000x reference)
//
#include <hip/hip_runtime.h>
#include <math.h>

#define FIN 256
#define F1  256   // H1*HID = 8*32
#define C2  16
#define NEG 0.2f

// ---------------- CSR build ----------------
__global__ __launch_bounds__(256) void zero2_kernel(int* a, int* b, int n) {
  int i = blockIdx.x * blockDim.x + threadIdx.x;
  if (i < n) { a[i] = 0; b[i] = 0; }
}

__global__ __launch_bounds__(256) void deg_kernel(const int* __restrict__ dst,
                                                  int* __restrict__ deg, int E) {
  int e = blockIdx.x * blockDim.x + threadIdx.x;
  if (e < E) atomicAdd(&deg[dst[e]], 1);
}

__global__ __launch_bounds__(1024) void scan_kernel(const int* __restrict__ deg,
                                                    int* __restrict__ offs, int n) {
  __shared__ int buf[1024];
  __shared__ int carry_s;
  int tid = threadIdx.x;
  if (tid == 0) carry_s = 0;
  __syncthreads();
  for (int base = 0; base < n; base += 1024) {
    int idx = base + tid;
    int v = (idx < n) ? deg[idx] : 0;
    buf[tid] = v;
    __syncthreads();
    for (int o = 1; o < 1024; o <<= 1) {
      int t = (tid >= o) ? buf[tid - o] : 0;
      __syncthreads();
      buf[tid] += t;
      __syncthreads();
    }
    int cb = carry_s;
    if (idx < n) offs[idx] = cb + buf[tid] - v;   // exclusive
    __syncthreads();
    if (tid == 0) carry_s = cb + buf[1023];
    __syncthreads();
  }
  if (tid == 0) offs[n] = carry_s;
}

__global__ __launch_bounds__(256) void fill_kernel(const int* __restrict__ src,
    const int* __restrict__ dst, const int* __restrict__ offs,
    int* __restrict__ cnt, int* __restrict__ csr, int E) {
  int e = blockIdx.x * blockDim.x + threadIdx.x;
  if (e < E) {
    int d = dst[e];
    int pos = offs[d] + atomicAdd(&cnt[d], 1);
    csr[pos] = src[e];
  }
}

// ---------------- GEMM: C[N,M] = A[N,K] @ B[K,M], 64x64 tile, 4x4/thread ----------------
__global__ __launch_bounds__(256) void gemm64_kernel(const float* __restrict__ A,
    const float* __restrict__ B, float* __restrict__ C, int N, int K, int M) {
  __shared__ float As[16][68];  // [k][row], padded, 16B-aligned rows
  __shared__ float Bs[16][68];  // [k][col]
  int tid = threadIdx.x;
  int row0 = blockIdx.x * 64;
  int col0 = blockIdx.y * 64;
  int tr = (tid / 16) * 4;
  int tc = (tid % 16) * 4;
  float acc[4][4] = {};
  for (int k0 = 0; k0 < K; k0 += 16) {
    int kk = tid & 15;
    int r  = tid >> 4;
#pragma unroll
    for (int i = 0; i < 4; i++) {
      int rr = r + i * 16;
      int grow = row0 + rr;
      As[kk][rr] = (grow < N) ? A[(size_t)grow * K + k0 + kk] : 0.f;
    }
    int c  = tid & 63;
    int kb = tid >> 6;
#pragma unroll
    for (int i = 0; i < 4; i++) {
      int k = kb + i * 4;
      Bs[k][c] = B[(size_t)(k0 + k) * M + col0 + c];
    }
    __syncthreads();
#pragma unroll
    for (int k = 0; k < 16; k++) {
      float4 a4 = *(const float4*)&As[k][tr];
      float4 b4 = *(const float4*)&Bs[k][tc];
      float a[4] = {a4.x, a4.y, a4.z, a4.w};
      float b[4] = {b4.x, b4.y, b4.z, b4.w};
#pragma unroll
      for (int i = 0; i < 4; i++)
#pragma unroll
        for (int j = 0; j < 4; j++)
          acc[i][j] = fmaf(a[i], b[j], acc[i][j]);
    }
    __syncthreads();
  }
#pragma unroll
  for (int i = 0; i < 4; i++) {
    int grow = row0 + tr + i;
    if (grow < N) {
      float4 v = make_float4(acc[i][0], acc[i][1], acc[i][2], acc[i][3]);
      *(float4*)&C[(size_t)grow * M + col0 + tc] = v;
    }
  }
}

// ---------------- small GEMM: C[N,16] = A[N,256] @ B[256,16] ----------------
__global__ __launch_bounds__(256) void gemm16_kernel(const float* __restrict__ A,
    const float* __restrict__ B, float* __restrict__ C, int N) {
  __shared__ float As[16][257];
  __shared__ float Bs[256 * 16];
  int tid = threadIdx.x;
  int row0 = blockIdx.x * 16;
  for (int idx = tid; idx < 256 * 16; idx += 256) Bs[idx] = B[idx];
  for (int idx = tid; idx < 16 * 256; idx += 256) {
    int r = idx >> 8, k = idx & 255;
    int gr = row0 + r;
    As[r][k] = (gr < N) ? A[(size_t)gr * 256 + k] : 0.f;
  }
  __syncthreads();
  int r = tid / 16, c = tid % 16;
  float acc = 0.f;
#pragma unroll 8
  for (int k = 0; k < 256; k++) acc = fmaf(As[r][k], Bs[k * 16 + c], acc);
  int gr = row0 + r;
  if (gr < N) C[(size_t)gr * 16 + c] = acc;
}

// ---------------- fused GATv2 layer 1: per-node online softmax + aggregate + bias + ELU ----------------
// hout may alias xr: block i reads only row i of xr (at start) and writes only row i of hout (at end).
__global__ __launch_bounds__(256) void gat1_kernel(const float* __restrict__ xl,
    const float* xr, const float* __restrict__ att, const float* __restrict__ bias,
    const int* __restrict__ offs, const int* __restrict__ csr, float* hout, int N) {
  int i = blockIdx.x;
  int t = threadIdx.x;              // feature dim: head = t/32, f = t%32
  float xri = xr[(size_t)i * F1 + t];
  float xli = xl[(size_t)i * F1 + t];
  float a_t = att[t];
  // self-loop
  float v = xli + xri;
  float lr = v > 0.f ? v : NEG * v;
  float p = lr * a_t;
#pragma unroll
  for (int o = 16; o >= 1; o >>= 1) p += __shfl_xor(p, o, 32);
  float m = p;          // running max (e_self)
  float ssum = 1.0f;    // exp(e_self - m)
  float O = xli;        // exp(0) * xl[i]
  int beg = offs[i], end = offs[i + 1];
  for (int e = beg; e < end; e++) {
    int j = csr[e];
    float xlj = xl[(size_t)j * F1 + t];
    float vv = xlj + xri;
    float lv = vv > 0.f ? vv : NEG * vv;
    float pp = lv * a_t;
#pragma unroll
    for (int o = 16; o >= 1; o >>= 1) pp += __shfl_xor(pp, o, 32);
    float mn = fmaxf(m, pp);
    float sc = __expf(m - mn);
    float wv = __expf(pp - mn);
    O = O * sc + wv * xlj;
    ssum = ssum * sc + wv;
    m = mn;
  }
  float outv = O / (ssum + 1e-16f);
  float hb = outv + bias[t];
  float h = hb > 0.f ? hb : (__expf(hb) - 1.0f);   // ELU
  hout[(size_t)i * F1 + t] = h;
}

// ---------------- fused GATv2 layer 2 (H=1, Fo=16): 16-lane group per node ----------------
__global__ __launch_bounds__(256) void gat2_kernel(const float* __restrict__ xl2,
    const float* __restrict__ xr2, const float* __restrict__ att,
    const float* __restrict__ b2, const int* __restrict__ offs,
    const int* __restrict__ csr, float* __restrict__ yout, int N) {
  int grp = threadIdx.x / 16;
  int c = threadIdx.x % 16;
  int i = blockIdx.x * 16 + grp;
  if (i >= N) return;
  float xri = xr2[(size_t)i * C2 + c];
  float xli = xl2[(size_t)i * C2 + c];
  float a = att[c];
  float v = xli + xri; v = v > 0.f ? v : NEG * v;
  float p = v * a;
#pragma unroll
  for (int o = 8; o >= 1; o >>= 1) p += __shfl_xor(p, o, 16);
  float m = p, ssum = 1.0f, O = xli;
  int beg = offs[i], end = offs[i + 1];
  for (int e = beg; e < end; e++) {
    int j = csr[e];
    float xlj = xl2[(size_t)j * C2 + c];
    float vv = xlj + xri; vv = vv > 0.f ? vv : NEG * vv;
    float pp = vv * a;
#pragma unroll
    for (int o = 8; o >= 1; o >>= 1) pp += __shfl_xor(pp, o, 16);
    float mn = fmaxf(m, pp);
    float sc = __expf(m - mn);
    float wv = __expf(pp - mn);
    O = O * sc + wv * xlj;
    ssum = ssum * sc + wv;
    m = mn;
  }
  yout[(size_t)i * C2 + c] = O / (ssum + 1e-16f) + b2[c];
}

// ---------------- finalize: log_softmax(y), log_softmax(z), 1-cos ----------------
__global__ __launch_bounds__(256) void finalize_kernel(const float* __restrict__ y,
    const float* __restrict__ z, float* __restrict__ out, int N) {
  int grp = threadIdx.x / 16;
  int c = threadIdx.x % 16;
  int i = blockIdx.x * 16 + grp;
  if (i >= N) return;
  float yv = y[(size_t)i * C2 + c];
  float zv = z[(size_t)i * C2 + c];
  float my = yv;
#pragma unroll
  for (int o = 8; o >= 1; o >>= 1) my = fmaxf(my, __shfl_xor(my, o, 16));
  float sy = __expf(yv - my);
#pragma unroll
  for (int o = 8; o >= 1; o >>= 1) sy += __shfl_xor(sy, o, 16);
  float lpy = yv - my - __logf(sy);
  float mz = zv;
#pragma unroll
  for (int o = 8; o >= 1; o >>= 1) mz = fmaxf(mz, __shfl_xor(mz, o, 16));
  float sz = __expf(zv - mz);
#pragma unroll
  for (int o = 8; o >= 1; o >>= 1) sz += __shfl_xor(sz, o, 16);
  float lpz = zv - mz - __logf(sz);
  float dot = yv * zv, ny2 = yv * yv, nz2 = zv * zv;
#pragma unroll
  for (int o = 8; o >= 1; o >>= 1) {
    dot += __shfl_xor(dot, o, 16);
    ny2 += __shfl_xor(ny2, o, 16);
    nz2 += __shfl_xor(nz2, o, 16);
  }
  float ny = fmaxf(sqrtf(ny2), 1e-8f);
  float nz = fmaxf(sqrtf(nz2), 1e-8f);
  float cosv = dot / (ny * nz);
  size_t o1 = (size_t)N * C2;
  size_t o2 = o1 + N;
  size_t o3 = o2 + (size_t)N * C2;
  size_t o4 = o3 + (size_t)N * C2;
  size_t idx = (size_t)i * C2 + c;
  out[idx] = lpy;
  if (c == 0) out[o1 + i] = 1.0f - cosv;
  out[o2 + idx] = lpz;
  out[o3 + idx] = lpy;
  out[o4 + idx] = lpy;
}

extern "C" void kernel_launch(void* const* d_in, const int* in_sizes, int n_in,
                              void* d_out, int out_size, void* d_ws, size_t ws_size,
                              hipStream_t stream) {
  const float* x1   = (const float*)d_in[0];
  const int*   ei1  = (const int*)d_in[1];
  const float* x2   = (const float*)d_in[2];
  const int*   ei2  = (const int*)d_in[3];
  const float* W1l  = (const float*)d_in[4];
  const float* W1r  = (const float*)d_in[5];
  const float* att1 = (const float*)d_in[6];
  const float* b1   = (const float*)d_in[7];
  const float* W2l  = (const float*)d_in[8];
  const float* W2r  = (const float*)d_in[9];
  const float* att2 = (const float*)d_in[10];
  const float* b2   = (const float*)d_in[11];
  const int N = in_sizes[0] / FIN;
  const int E = in_sizes[1] / 2;
  float* out = (float*)d_out;

  char* w = (char*)d_ws;
  size_t off = 0;
  auto carve = [&](size_t bytes) -> void* {
    void* p = w + off;
    off += (bytes + 255) & ~(size_t)255;
    return p;
  };
  float* xl   = (float*)carve((size_t)N * F1 * 4);
  float* xrh  = (float*)carve((size_t)N * F1 * 4);   // xr, then reused as h (safe alias)
  float* xl2  = (float*)carve((size_t)N * C2 * 4);
  float* xr2  = (float*)carve((size_t)N * C2 * 4);
  float* yb   = (float*)carve((size_t)N * C2 * 4);
  float* zb   = (float*)carve((size_t)N * C2 * 4);
  int* deg  = (int*)carve((size_t)N * 4);
  int* offs = (int*)carve((size_t)(N + 1) * 4);
  int* cnt  = (int*)carve((size_t)N * 4);
  int* csr  = (int*)carve((size_t)E * 4);
  (void)ws_size; (void)n_in; (void)out_size;

  for (int g = 0; g < 2; g++) {
    const float* x  = g ? x2 : x1;
    const int*   ei = g ? ei2 : ei1;
    float* yout = g ? zb : yb;
    const int* srcp = ei;
    const int* dstp = ei + E;

    zero2_kernel<<<(N + 255) / 256, 256, 0, stream>>>(deg, cnt, N);
    deg_kernel<<<(E + 255) / 256, 256, 0, stream>>>(dstp, deg, E);
    scan_kernel<<<1, 1024, 0, stream>>>(deg, offs, N);
    fill_kernel<<<(E + 255) / 256, 256, 0, stream>>>(srcp, dstp, offs, cnt, csr, E);

    dim3 g64((N + 63) / 64, F1 / 64);
    gemm64_kernel<<<g64, 256, 0, stream>>>(x, W1l, xl, N, FIN, F1);
    gemm64_kernel<<<g64, 256, 0, stream>>>(x, W1r, xrh, N, FIN, F1);
    gat1_kernel<<<N, 256, 0, stream>>>(xl, xrh, att1, b1, offs, csr, xrh, N);
    gemm16_kernel<<<(N + 15) / 16, 256, 0, stream>>>(xrh, W2l, xl2, N);
    gemm16_kernel<<<(N + 15) / 16, 256, 0, stream>>>(xrh, W2r, xr2, N);
    gat2_kernel<<<(N + 15) / 16, 256, 0, stream>>>(xl2, xr2, att2, b2, offs, csr, yout, N);
  }
  finalize_kernel<<<(N + 15) / 16, 256, 0, stream>>>(yb, zb, out, N);
}

// Round 2
// 811.205 us; speedup vs baseline: 1.8686x; 1.8686x over previous
//
#include <hip/hip_runtime.h>
#include <hip/hip_bf16.h>
#include <math.h>

#define FIN 256
#define F1  256   // H1*HID = 8*32
#define C2  16
#define NEG 0.2f

typedef short bf16x8 __attribute__((ext_vector_type(8)));
typedef float f32x4v __attribute__((ext_vector_type(4)));

__device__ __forceinline__ float bf2f(unsigned short u) {
  union { float f; unsigned int i; } c; c.i = ((unsigned int)u) << 16; return c.f;
}
__device__ __forceinline__ unsigned short f2bf(float f) {
  __hip_bfloat16 b = __float2bfloat16(f);
  return *(unsigned short*)&b;
}

// ---------------- CSR build ----------------
__global__ __launch_bounds__(256) void zero2_kernel(int* a, int* b, int n) {
  int i = blockIdx.x * blockDim.x + threadIdx.x;
  if (i < n) { a[i] = 0; b[i] = 0; }
}

__global__ __launch_bounds__(256) void deg_kernel(const int* __restrict__ dst,
                                                  int* __restrict__ deg, int E) {
  int e = blockIdx.x * blockDim.x + threadIdx.x;
  if (e < E) atomicAdd(&deg[dst[e]], 1);
}

// shfl-based single-block scan (exclusive) over n elements, chunked by 1024
__global__ __launch_bounds__(1024) void scan_kernel(const int* __restrict__ deg,
                                                    int* __restrict__ offs, int n) {
  __shared__ int wsum[16], wpref[16];
  __shared__ int carry_s, tot_s;
  int tid = threadIdx.x, lane = tid & 63, wid = tid >> 6;
  if (tid == 0) carry_s = 0;
  __syncthreads();
  for (int base = 0; base < n; base += 1024) {
    int idx = base + tid;
    int v = (idx < n) ? deg[idx] : 0;
    int s = v;
#pragma unroll
    for (int o = 1; o < 64; o <<= 1) {
      int t = __shfl_up(s, o, 64);
      if (lane >= o) s += t;
    }
    if (lane == 63) wsum[wid] = s;
    __syncthreads();
    if (tid < 16) {
      int t = wsum[tid];
      int ss = t;
#pragma unroll
      for (int o = 1; o < 16; o <<= 1) {
        int u = __shfl_up(ss, o, 16);
        if (tid >= o) ss += u;
      }
      wpref[tid] = ss - t;          // exclusive wave prefix
      if (tid == 15) tot_s = ss;    // chunk total
    }
    __syncthreads();
    int cb = carry_s;
    if (idx < n) offs[idx] = cb + wpref[wid] + s - v;
    __syncthreads();
    if (tid == 0) carry_s = cb + tot_s;
    __syncthreads();
  }
  if (tid == 0) offs[n] = carry_s;
}

__global__ __launch_bounds__(256) void fill_kernel(const int* __restrict__ src,
    const int* __restrict__ dst, const int* __restrict__ offs,
    int* __restrict__ cnt, int* __restrict__ csr, int E) {
  int e = blockIdx.x * blockDim.x + threadIdx.x;
  if (e < E) {
    int d = dst[e];
    int pos = offs[d] + atomicAdd(&cnt[d], 1);
    csr[pos] = src[e];
  }
}

// ---------------- converts ----------------
__global__ __launch_bounds__(256) void cvt_x_kernel(const float* __restrict__ x,
    unsigned short* __restrict__ xb, int n4) {
  int i = blockIdx.x * 256 + threadIdx.x;
  if (i < n4) {
    float4 v = ((const float4*)x)[i];
    ushort4 o;
    o.x = f2bf(v.x); o.y = f2bf(v.y); o.z = f2bf(v.z); o.w = f2bf(v.w);
    ((ushort4*)xb)[i] = o;
  }
}

// Wt[n][k] = (n<256 ? W1l : W1r)[k][n(%256)]  as bf16, n in [0,512)
__global__ __launch_bounds__(256) void cvt_w_kernel(const float* __restrict__ Wl,
    const float* __restrict__ Wr, unsigned short* __restrict__ Wt) {
  int n = blockIdx.x;
  int k = threadIdx.x;
  float v = (n < 256) ? Wl[k * 256 + n] : Wr[k * 256 + (n - 256)];
  Wt[n * 256 + k] = f2bf(v);
}

// ---------------- MFMA GEMM: C[M,512](bf16) = A[M,256](bf16) @ Bt^T, Bt[512][256] ----------------
#define LDT 72
__global__ __launch_bounds__(256) void gemm_mfma_kernel(
    const unsigned short* __restrict__ A, const unsigned short* __restrict__ Bt,
    unsigned short* __restrict__ C, int M) {
  __shared__ __align__(16) unsigned short As[128 * LDT];
  __shared__ __align__(16) unsigned short Bs[128 * LDT];
  int tid = threadIdx.x;
  int row0 = blockIdx.x * 128;
  int col0 = blockIdx.y * 128;
  int wid = tid >> 6, lane = tid & 63;
  int wr = wid >> 1, wc = wid & 1;
  int r16 = lane & 15, kb = (lane >> 4) * 8;

  f32x4v acc[4][4];
#pragma unroll
  for (int m = 0; m < 4; m++)
#pragma unroll
    for (int n = 0; n < 4; n++)
#pragma unroll
      for (int q = 0; q < 4; q++) acc[m][n][q] = 0.f;

  for (int k0 = 0; k0 < 256; k0 += 64) {
#pragma unroll
    for (int it = 0; it < 4; it++) {
      int c = tid + it * 256;         // 0..1023
      int r = c >> 3;                 // 8 16B-chunks per 64-elem row
      int ko = (c & 7) * 8;
      int gr = row0 + r;
      int4 av = make_int4(0, 0, 0, 0);
      if (gr < M) av = *(const int4*)&A[(size_t)gr * 256 + k0 + ko];
      *(int4*)&As[r * LDT + ko] = av;
      int4 bv = *(const int4*)&Bt[(size_t)(col0 + r) * 256 + k0 + ko];
      *(int4*)&Bs[r * LDT + ko] = bv;
    }
    __syncthreads();
#pragma unroll
    for (int kk = 0; kk < 64; kk += 32) {
      bf16x8 af[4], bfr[4];
#pragma unroll
      for (int m = 0; m < 4; m++)
        af[m] = *(const bf16x8*)&As[(wr * 64 + m * 16 + r16) * LDT + kk + kb];
#pragma unroll
      for (int n = 0; n < 4; n++)
        bfr[n] = *(const bf16x8*)&Bs[(wc * 64 + n * 16 + r16) * LDT + kk + kb];
#pragma unroll
      for (int m = 0; m < 4; m++)
#pragma unroll
        for (int n = 0; n < 4; n++)
          acc[m][n] = __builtin_amdgcn_mfma_f32_16x16x32_bf16(af[m], bfr[n], acc[m][n], 0, 0, 0);
    }
    __syncthreads();
  }
  int rq = (lane >> 4) * 4;
#pragma unroll
  for (int m = 0; m < 4; m++) {
#pragma unroll
    for (int n = 0; n < 4; n++) {
#pragma unroll
      for (int q = 0; q < 4; q++) {
        int gr = row0 + wr * 64 + m * 16 + rq + q;
        if (gr < M) {
          int gc = col0 + wc * 64 + n * 16 + r16;
          C[(size_t)gr * 512 + gc] = f2bf(acc[m][n][q]);
        }
      }
    }
  }
}

// ---------------- fused GATv2 layer 1 (1 wave per node, 4 feats/lane) ----------------
__global__ __launch_bounds__(256) void gat1_kernel(const unsigned short* __restrict__ xlr,
    const float* __restrict__ att, const float* __restrict__ bias,
    const int* __restrict__ offs, const int* __restrict__ csr,
    float* __restrict__ h, int N) {
  int w = threadIdx.x >> 6, lane = threadIdx.x & 63;
  int i = blockIdx.x * 4 + w;
  if (i >= N) return;
  const ushort4* rowp = (const ushort4*)(xlr + (size_t)i * 512);
  ushort4 ul = rowp[lane];
  ushort4 ur = rowp[64 + lane];
  float xl0 = bf2f(ul.x), xl1 = bf2f(ul.y), xl2 = bf2f(ul.z), xl3 = bf2f(ul.w);
  float xr0 = bf2f(ur.x), xr1 = bf2f(ur.y), xr2 = bf2f(ur.z), xr3 = bf2f(ur.w);
  float4 a4 = ((const float4*)att)[lane];
  float4 b4 = ((const float4*)bias)[lane];
  // self-loop score
  float s0 = xl0 + xr0, s1 = xl1 + xr1, s2 = xl2 + xr2, s3 = xl3 + xr3;
  float p = fmaxf(s0, NEG * s0) * a4.x;
  p = fmaf(fmaxf(s1, NEG * s1), a4.y, p);
  p = fmaf(fmaxf(s2, NEG * s2), a4.z, p);
  p = fmaf(fmaxf(s3, NEG * s3), a4.w, p);
  p += __shfl_xor(p, 1, 8);
  p += __shfl_xor(p, 2, 8);
  p += __shfl_xor(p, 4, 8);
  float m = p, ssum = 1.f;
  float O0 = xl0, O1 = xl1, O2 = xl2, O3 = xl3;
  int e = offs[i], end = offs[i + 1];
  for (; e < end; e++) {
    int j = csr[e];
    ushort4 uj = ((const ushort4*)(xlr + (size_t)j * 512))[lane];
    float x0 = bf2f(uj.x), x1 = bf2f(uj.y), x2 = bf2f(uj.z), x3 = bf2f(uj.w);
    float t0 = x0 + xr0, t1 = x1 + xr1, t2 = x2 + xr2, t3 = x3 + xr3;
    float pp = fmaxf(t0, NEG * t0) * a4.x;
    pp = fmaf(fmaxf(t1, NEG * t1), a4.y, pp);
    pp = fmaf(fmaxf(t2, NEG * t2), a4.z, pp);
    pp = fmaf(fmaxf(t3, NEG * t3), a4.w, pp);
    pp += __shfl_xor(pp, 1, 8);
    pp += __shfl_xor(pp, 2, 8);
    pp += __shfl_xor(pp, 4, 8);
    float mn = fmaxf(m, pp);
    float sc = __expf(m - mn);
    float wv = __expf(pp - mn);
    O0 = fmaf(O0, sc, wv * x0);
    O1 = fmaf(O1, sc, wv * x1);
    O2 = fmaf(O2, sc, wv * x2);
    O3 = fmaf(O3, sc, wv * x3);
    ssum = fmaf(ssum, sc, wv);
    m = mn;
  }
  float inv = 1.f / (ssum + 1e-16f);
  float h0 = fmaf(O0, inv, 0.f) + b4.x;
  float h1 = O1 * inv + b4.y;
  float h2 = O2 * inv + b4.z;
  float h3 = O3 * inv + b4.w;
  h0 = h0 > 0.f ? h0 : (__expf(h0) - 1.f);
  h1 = h1 > 0.f ? h1 : (__expf(h1) - 1.f);
  h2 = h2 > 0.f ? h2 : (__expf(h2) - 1.f);
  h3 = h3 > 0.f ? h3 : (__expf(h3) - 1.f);
  ((float4*)(h + (size_t)i * 256))[lane] = make_float4(h0, h1, h2, h3);
}

// ---------------- layer-2 fused GEMM pair: C[N,32] = h[N,256] @ [W2l|W2r] ----------------
#define LDA2 36
#define LDB2 40
__global__ __launch_bounds__(64) void gemm32_kernel(const float* __restrict__ A,
    const float* __restrict__ Wl, const float* __restrict__ Wr,
    float* __restrict__ C, int N) {
  __shared__ __align__(16) float As[256 * LDA2];  // [k][r] transposed
  __shared__ __align__(16) float Bs[256 * LDB2];  // [k][c]
  int t = threadIdx.x;
  int row0 = blockIdx.x * 32;
#pragma unroll 4
  for (int it = 0; it < 32; it++) {
    int c = t + 64 * it;            // float4 chunk id, 0..2047
    int r = c >> 6;                 // 64 float4 per 256-elem row
    int k0 = (c & 63) * 4;
    int gr = row0 + r;
    float4 v = make_float4(0.f, 0.f, 0.f, 0.f);
    if (gr < N) v = *(const float4*)&A[(size_t)gr * 256 + k0];
    As[(k0 + 0) * LDA2 + r] = v.x;
    As[(k0 + 1) * LDA2 + r] = v.y;
    As[(k0 + 2) * LDA2 + r] = v.z;
    As[(k0 + 3) * LDA2 + r] = v.w;
  }
#pragma unroll 4
  for (int it = 0; it < 16; it++) {
    int c = t + 64 * it;            // 0..1023
    int k = c >> 2;
    int q = (c & 3) * 4;
    *(float4*)&Bs[k * LDB2 + q] = *(const float4*)&Wl[k * 16 + q];
    *(float4*)&Bs[k * LDB2 + 16 + q] = *(const float4*)&Wr[k * 16 + q];
  }
  __syncthreads();
  int rg = t >> 3, cg = t & 7;
  float acc[4][4] = {};
#pragma unroll 4
  for (int k = 0; k < 256; k++) {
    float4 a = *(const float4*)&As[k * LDA2 + rg * 4];
    float4 b = *(const float4*)&Bs[k * LDB2 + cg * 4];
    float av[4] = {a.x, a.y, a.z, a.w};
    float bv[4] = {b.x, b.y, b.z, b.w};
#pragma unroll
    for (int ii = 0; ii < 4; ii++)
#pragma unroll
      for (int jj = 0; jj < 4; jj++)
        acc[ii][jj] = fmaf(av[ii], bv[jj], acc[ii][jj]);
  }
#pragma unroll
  for (int ii = 0; ii < 4; ii++) {
    int gr = row0 + rg * 4 + ii;
    if (gr < N) {
      float4 v = make_float4(acc[ii][0], acc[ii][1], acc[ii][2], acc[ii][3]);
      *(float4*)&C[(size_t)gr * 32 + cg * 4] = v;
    }
  }
}

// ---------------- fused GATv2 layer 2 (H=1, Fo=16) ----------------
__global__ __launch_bounds__(256) void gat2_kernel(const float* __restrict__ xlr2,
    const float* __restrict__ att, const float* __restrict__ b2,
    const int* __restrict__ offs, const int* __restrict__ csr,
    float* __restrict__ yout, int N) {
  int grp = threadIdx.x >> 4, c = threadIdx.x & 15;
  int i = blockIdx.x * 16 + grp;
  if (i >= N) return;
  float xli = xlr2[(size_t)i * 32 + c];
  float xri = xlr2[(size_t)i * 32 + 16 + c];
  float a = att[c];
  float v = xli + xri; v = fmaxf(v, NEG * v);
  float p = v * a;
#pragma unroll
  for (int o = 8; o >= 1; o >>= 1) p += __shfl_xor(p, o, 16);
  float m = p, ssum = 1.0f, O = xli;
  int e = offs[i], end = offs[i + 1];
  for (; e < end; e++) {
    int j = csr[e];
    float xlj = xlr2[(size_t)j * 32 + c];
    float vv = xlj + xri; vv = fmaxf(vv, NEG * vv);
    float pp = vv * a;
#pragma unroll
    for (int o = 8; o >= 1; o >>= 1) pp += __shfl_xor(pp, o, 16);
    float mn = fmaxf(m, pp);
    float sc = __expf(m - mn);
    float wv = __expf(pp - mn);
    O = fmaf(O, sc, wv * xlj);
    ssum = fmaf(ssum, sc, wv);
    m = mn;
  }
  yout[(size_t)i * C2 + c] = O / (ssum + 1e-16f) + b2[c];
}

// ---------------- finalize ----------------
__global__ __launch_bounds__(256) void finalize_kernel(const float* __restrict__ y,
    const float* __restrict__ z, float* __restrict__ out, int N) {
  int grp = threadIdx.x >> 4, c = threadIdx.x & 15;
  int i = blockIdx.x * 16 + grp;
  if (i >= N) return;
  float yv = y[(size_t)i * C2 + c];
  float zv = z[(size_t)i * C2 + c];
  float my = yv;
#pragma unroll
  for (int o = 8; o >= 1; o >>= 1) my = fmaxf(my, __shfl_xor(my, o, 16));
  float sy = __expf(yv - my);
#pragma unroll
  for (int o = 8; o >= 1; o >>= 1) sy += __shfl_xor(sy, o, 16);
  float lpy = yv - my - __logf(sy);
  float mz = zv;
#pragma unroll
  for (int o = 8; o >= 1; o >>= 1) mz = fmaxf(mz, __shfl_xor(mz, o, 16));
  float sz = __expf(zv - mz);
#pragma unroll
  for (int o = 8; o >= 1; o >>= 1) sz += __shfl_xor(sz, o, 16);
  float lpz = zv - mz - __logf(sz);
  float dot = yv * zv, ny2 = yv * yv, nz2 = zv * zv;
#pragma unroll
  for (int o = 8; o >= 1; o >>= 1) {
    dot += __shfl_xor(dot, o, 16);
    ny2 += __shfl_xor(ny2, o, 16);
    nz2 += __shfl_xor(nz2, o, 16);
  }
  float ny = fmaxf(sqrtf(ny2), 1e-8f);
  float nz = fmaxf(sqrtf(nz2), 1e-8f);
  float cosv = dot / (ny * nz);
  size_t o1 = (size_t)N * C2;
  size_t o2 = o1 + N;
  size_t o3 = o2 + (size_t)N * C2;
  size_t o4 = o3 + (size_t)N * C2;
  size_t idx = (size_t)i * C2 + c;
  out[idx] = lpy;
  if (c == 0) out[o1 + i] = 1.0f - cosv;
  out[o2 + idx] = lpz;
  out[o3 + idx] = lpy;
  out[o4 + idx] = lpy;
}

extern "C" void kernel_launch(void* const* d_in, const int* in_sizes, int n_in,
                              void* d_out, int out_size, void* d_ws, size_t ws_size,
                              hipStream_t stream) {
  const float* x1   = (const float*)d_in[0];
  const int*   ei1  = (const int*)d_in[1];
  const float* x2   = (const float*)d_in[2];
  const int*   ei2  = (const int*)d_in[3];
  const float* W1l  = (const float*)d_in[4];
  const float* W1r  = (const float*)d_in[5];
  const float* att1 = (const float*)d_in[6];
  const float* b1   = (const float*)d_in[7];
  const float* W2l  = (const float*)d_in[8];
  const float* W2r  = (const float*)d_in[9];
  const float* att2 = (const float*)d_in[10];
  const float* b2   = (const float*)d_in[11];
  const int N = in_sizes[0] / FIN;
  const int E = in_sizes[1] / 2;
  float* out = (float*)d_out;

  char* w = (char*)d_ws;
  size_t off = 0;
  auto carve = [&](size_t bytes) -> void* {
    void* p = w + off;
    off += (bytes + 255) & ~(size_t)255;
    return p;
  };
  unsigned short* xlr_b = (unsigned short*)carve((size_t)N * 512 * 2);
  float* h              = (float*)carve((size_t)N * 256 * 4);
  unsigned short* xcvt  = (unsigned short*)h;   // alias: dead before gat1 writes h
  unsigned short* Wt    = (unsigned short*)carve(512 * 256 * 2);
  float* xlr2 = (float*)carve((size_t)N * 32 * 4);
  float* yb   = (float*)carve((size_t)N * 16 * 4);
  float* zb   = (float*)carve((size_t)N * 16 * 4);
  int* deg  = (int*)carve((size_t)N * 4);
  int* offs = (int*)carve((size_t)(N + 1) * 4);
  int* cnt  = (int*)carve((size_t)N * 4);
  int* csr  = (int*)carve((size_t)E * 4);
  (void)ws_size; (void)n_in; (void)out_size;

  cvt_w_kernel<<<512, 256, 0, stream>>>(W1l, W1r, Wt);

  for (int g = 0; g < 2; g++) {
    const float* x  = g ? x2 : x1;
    const int*   ei = g ? ei2 : ei1;
    float* yout = g ? zb : yb;
    const int* srcp = ei;
    const int* dstp = ei + E;

    zero2_kernel<<<(N + 255) / 256, 256, 0, stream>>>(deg, cnt, N);
    deg_kernel<<<(E + 255) / 256, 256, 0, stream>>>(dstp, deg, E);
    scan_kernel<<<1, 1024, 0, stream>>>(deg, offs, N);
    fill_kernel<<<(E + 255) / 256, 256, 0, stream>>>(srcp, dstp, offs, cnt, csr, E);

    cvt_x_kernel<<<(N * FIN / 4 + 255) / 256, 256, 0, stream>>>(x, xcvt, N * FIN / 4);
    dim3 gg((N + 127) / 128, 4);
    gemm_mfma_kernel<<<gg, 256, 0, stream>>>(xcvt, Wt, xlr_b, N);
    gat1_kernel<<<(N + 3) / 4, 256, 0, stream>>>(xlr_b, att1, b1, offs, csr, h, N);
    gemm32_kernel<<<(N + 31) / 32, 64, 0, stream>>>(h, W2l, W2r, xlr2, N);
    gat2_kernel<<<(N + 15) / 16, 256, 0, stream>>>(xlr2, att2, b2, offs, csr, yout, N);
  }
  finalize_kernel<<<(N + 15) / 16, 256, 0, stream>>>(yb, zb, out, N);
}

// Round 4
// 557.699 us; speedup vs baseline: 2.7180x; 1.4546x over previous
//
#include <hip/hip_runtime.h>
#include <hip/hip_bf16.h>
#include <math.h>

#define FIN 256
#define F1  256   // H1*HID = 8*32
#define C2  16
#define NEG 0.2f

typedef short bf16x8 __attribute__((ext_vector_type(8)));
typedef float f32x4v __attribute__((ext_vector_type(4)));
typedef float f32x2 __attribute__((ext_vector_type(2)));

__device__ __forceinline__ float bf2f(unsigned short u) {
  union { float f; unsigned int i; } c; c.i = ((unsigned int)u) << 16; return c.f;
}
__device__ __forceinline__ unsigned short f2bf(float f) {
  __hip_bfloat16 b = __float2bfloat16(f);
  return *(unsigned short*)&b;
}
// two bf16 packed in a u32 -> two f32 (x = low half, y = high half)
__device__ __forceinline__ f32x2 bfpair(unsigned int u) {
  union { float f; unsigned int i; } lo, hi;
  lo.i = u << 16;
  hi.i = u & 0xffff0000u;
  f32x2 r; r.x = lo.f; r.y = hi.f; return r;
}

// ---------------- CSR build ----------------
__global__ __launch_bounds__(256) void deg_kernel(const int* __restrict__ dst,
                                                  int* __restrict__ deg, int E) {
  int e = blockIdx.x * blockDim.x + threadIdx.x;
  if (e < E) atomicAdd(&deg[dst[e]], 1);
}

// per-block exclusive scan; writes block-local offs and per-block totals
__global__ __launch_bounds__(1024) void scan_part_kernel(const int* __restrict__ deg,
    int* __restrict__ offs, int* __restrict__ partials, int n) {
  __shared__ int wsum[16], wpref[16];
  int tid = threadIdx.x, lane = tid & 63, wid = tid >> 6;
  int idx = blockIdx.x * 1024 + tid;
  int v = (idx < n) ? deg[idx] : 0;
  int s = v;
#pragma unroll
  for (int o = 1; o < 64; o <<= 1) {
    int t = __shfl_up(s, o, 64);
    if (lane >= o) s += t;
  }
  if (lane == 63) wsum[wid] = s;
  __syncthreads();
  if (tid < 16) {
    int t = wsum[tid];
    int ss = t;
#pragma unroll
    for (int o = 1; o < 16; o <<= 1) {
      int u = __shfl_up(ss, o, 16);
      if (tid >= o) ss += u;
    }
    wpref[tid] = ss - t;
    if (tid == 15) partials[blockIdx.x] = ss;
  }
  __syncthreads();
  if (idx < n) offs[idx] = wpref[wid] + s - v;
}

// single wave: exclusive-scan the (<=64) block totals
__global__ __launch_bounds__(64) void scan_carry_kernel(int* __restrict__ partials,
    int* __restrict__ carries, int* __restrict__ offs, int nb, int n) {
  int tid = threadIdx.x;
  int v = (tid < nb) ? partials[tid] : 0;
  int s = v;
#pragma unroll
  for (int o = 1; o < 64; o <<= 1) {
    int t = __shfl_up(s, o, 64);
    if (tid >= o) s += t;
  }
  if (tid < nb) carries[tid] = s - v;
  if (tid == 63) offs[n] = s;
}

__global__ __launch_bounds__(1024) void scan_add_kernel(int* __restrict__ offs,
    const int* __restrict__ carries, int n) {
  int b = blockIdx.x + 1;
  int idx = b * 1024 + threadIdx.x;
  if (idx < n) offs[idx] += carries[b];
}

__global__ __launch_bounds__(256) void fill_kernel(const int* __restrict__ src,
    const int* __restrict__ dst, const int* __restrict__ offs,
    int* __restrict__ cnt, int* __restrict__ csr, int E) {
  int e = blockIdx.x * blockDim.x + threadIdx.x;
  if (e < E) {
    int d = dst[e];
    int pos = offs[d] + atomicAdd(&cnt[d], 1);
    csr[pos] = src[e];
  }
}

// ---------------- converts ----------------
__global__ __launch_bounds__(256) void cvt_x_kernel(const float* __restrict__ x,
    unsigned short* __restrict__ xb, int n4) {
  int i = blockIdx.x * 256 + threadIdx.x;
  if (i < n4) {
    float4 v = ((const float4*)x)[i];
    ushort4 o;
    o.x = f2bf(v.x); o.y = f2bf(v.y); o.z = f2bf(v.z); o.w = f2bf(v.w);
    ((ushort4*)xb)[i] = o;
  }
}

// Wt[n][k] = (n<256 ? W1l : W1r)[k][n(%256)]  as bf16, n in [0,512)
__global__ __launch_bounds__(256) void cvt_w_kernel(const float* __restrict__ Wl,
    const float* __restrict__ Wr, unsigned short* __restrict__ Wt) {
  int n = blockIdx.x;
  int k = threadIdx.x;
  float v = (n < 256) ? Wl[k * 256 + n] : Wr[k * 256 + (n - 256)];
  Wt[n * 256 + k] = f2bf(v);
}

// Wt2[c][k] = (c<16 ? W2l : W2r)[k][c%16] as bf16, c in [0,32)
__global__ __launch_bounds__(256) void cvt_w2_kernel(const float* __restrict__ Wl,
    const float* __restrict__ Wr, unsigned short* __restrict__ Wt2) {
  int c = blockIdx.x;
  int k = threadIdx.x;
  float v = (c < 16) ? Wl[k * 16 + c] : Wr[k * 16 + (c - 16)];
  Wt2[c * 256 + k] = f2bf(v);
}

// ---------------- MFMA GEMM: C[M,512](bf16) = A[M,256](bf16) @ Bt^T, Bt[512][256] ----------------
#define LDT 72
__global__ __launch_bounds__(256) void gemm_mfma_kernel(
    const unsigned short* __restrict__ A, const unsigned short* __restrict__ Bt,
    unsigned short* __restrict__ C, int M) {
  __shared__ __align__(16) unsigned short As[128 * LDT];
  __shared__ __align__(16) unsigned short Bs[128 * LDT];
  int tid = threadIdx.x;
  int row0 = blockIdx.x * 128;
  int col0 = blockIdx.y * 128;
  int wid = tid >> 6, lane = tid & 63;
  int wr = wid >> 1, wc = wid & 1;
  int r16 = lane & 15, kb = (lane >> 4) * 8;

  f32x4v acc[4][4];
#pragma unroll
  for (int m = 0; m < 4; m++)
#pragma unroll
    for (int n = 0; n < 4; n++)
#pragma unroll
      for (int q = 0; q < 4; q++) acc[m][n][q] = 0.f;

  for (int k0 = 0; k0 < 256; k0 += 64) {
#pragma unroll
    for (int it = 0; it < 4; it++) {
      int c = tid + it * 256;         // 0..1023
      int r = c >> 3;
      int ko = (c & 7) * 8;
      int gr = row0 + r;
      int4 av = make_int4(0, 0, 0, 0);
      if (gr < M) av = *(const int4*)&A[(size_t)gr * 256 + k0 + ko];
      *(int4*)&As[r * LDT + ko] = av;
      int4 bv = *(const int4*)&Bt[(size_t)(col0 + r) * 256 + k0 + ko];
      *(int4*)&Bs[r * LDT + ko] = bv;
    }
    __syncthreads();
#pragma unroll
    for (int kk = 0; kk < 64; kk += 32) {
      bf16x8 af[4], bfr[4];
#pragma unroll
      for (int m = 0; m < 4; m++)
        af[m] = *(const bf16x8*)&As[(wr * 64 + m * 16 + r16) * LDT + kk + kb];
#pragma unroll
      for (int n = 0; n < 4; n++)
        bfr[n] = *(const bf16x8*)&Bs[(wc * 64 + n * 16 + r16) * LDT + kk + kb];
#pragma unroll
      for (int m = 0; m < 4; m++)
#pragma unroll
        for (int n = 0; n < 4; n++)
          acc[m][n] = __builtin_amdgcn_mfma_f32_16x16x32_bf16(af[m], bfr[n], acc[m][n], 0, 0, 0);
    }
    __syncthreads();
  }
  int rq = (lane >> 4) * 4;
#pragma unroll
  for (int m = 0; m < 4; m++) {
#pragma unroll
    for (int n = 0; n < 4; n++) {
#pragma unroll
      for (int q = 0; q < 4; q++) {
        int gr = row0 + wr * 64 + m * 16 + rq + q;
        if (gr < M) {
          int gc = col0 + wc * 64 + n * 16 + r16;
          C[(size_t)gr * 512 + gc] = f2bf(acc[m][n][q]);
        }
      }
    }
  }
}

// ---------------- layer-2 MFMA GEMM: C[M,32](f32) = h[M,256](bf16) @ Wt2^T ----------------
#define LDB2 264
__global__ __launch_bounds__(256) void gemm2_mfma_kernel(
    const unsigned short* __restrict__ A, const unsigned short* __restrict__ Bt,
    float* __restrict__ C, int M) {
  __shared__ __align__(16) unsigned short As[256 * LDT];
  __shared__ __align__(16) unsigned short Bs[32 * LDB2];
  int tid = threadIdx.x;
  int row0 = blockIdx.x * 256;
  int wid = tid >> 6, lane = tid & 63;
  int r16 = lane & 15, kb = (lane >> 4) * 8, rq = (lane >> 4) * 4;

#pragma unroll
  for (int it = 0; it < 4; it++) {
    int g = tid + it * 256;           // 0..1023 granules of B
    int r = g >> 5;                   // 32 granules per 256-elem row
    int ko = (g & 31) * 8;
    *(int4*)&Bs[r * LDB2 + ko] = *(const int4*)&Bt[r * 256 + ko];
  }

  f32x4v acc[4][2];
#pragma unroll
  for (int m = 0; m < 4; m++)
#pragma unroll
    for (int n = 0; n < 2; n++)
#pragma unroll
      for (int q = 0; q < 4; q++) acc[m][n][q] = 0.f;

  for (int k0 = 0; k0 < 256; k0 += 64) {
#pragma unroll
    for (int it = 0; it < 8; it++) {
      int g = tid + it * 256;         // 0..2047
      int r = g >> 3;
      int ko = (g & 7) * 8;
      int gr = row0 + r;
      int4 av = make_int4(0, 0, 0, 0);
      if (gr < M) av = *(const int4*)&A[(size_t)gr * 256 + k0 + ko];
      *(int4*)&As[r * LDT + ko] = av;
    }
    __syncthreads();
#pragma unroll
    for (int kk = 0; kk < 64; kk += 32) {
      bf16x8 af[4], bfr[2];
#pragma unroll
      for (int m = 0; m < 4; m++)
        af[m] = *(const bf16x8*)&As[(wid * 64 + m * 16 + r16) * LDT + kk + kb];
#pragma unroll
      for (int n = 0; n < 2; n++)
        bfr[n] = *(const bf16x8*)&Bs[(n * 16 + r16) * LDB2 + k0 + kk + kb];
#pragma unroll
      for (int m = 0; m < 4; m++)
#pragma unroll
        for (int n = 0; n < 2; n++)
          acc[m][n] = __builtin_amdgcn_mfma_f32_16x16x32_bf16(af[m], bfr[n], acc[m][n], 0, 0, 0);
    }
    __syncthreads();
  }
#pragma unroll
  for (int m = 0; m < 4; m++) {
#pragma unroll
    for (int n = 0; n < 2; n++) {
#pragma unroll
      for (int q = 0; q < 4; q++) {
        int gr = row0 + wid * 64 + m * 16 + rq + q;
        if (gr < M) C[(size_t)gr * 32 + n * 16 + r16] = acc[m][n][q];
      }
    }
  }
}

// ---------------- fused GATv2 layer 1 (1 wave/node, 4 feats/lane, defer-max, 2-unroll) ----------------
__global__ __launch_bounds__(256) void gat1_kernel(const unsigned short* __restrict__ xlr,
    const float* __restrict__ att, const float* __restrict__ bias,
    const int* __restrict__ offs, const int* __restrict__ csr,
    unsigned short* __restrict__ h, int N) {
  int w = threadIdx.x >> 6, lane = threadIdx.x & 63;
  int i = blockIdx.x * 4 + w;
  if (i >= N) return;
  const uint2* rows = (const uint2*)xlr;   // 8B granule = 4 bf16
  uint2 ul = rows[(size_t)i * 128 + lane];
  uint2 ur = rows[(size_t)i * 128 + 64 + lane];
  f32x2 xl01 = bfpair(ul.x), xl23 = bfpair(ul.y);
  f32x2 xr01 = bfpair(ur.x), xr23 = bfpair(ur.y);
  float4 a4 = ((const float4*)att)[lane];
  f32x2 a01; a01.x = a4.x; a01.y = a4.y;
  f32x2 a23; a23.x = a4.z; a23.y = a4.w;

  f32x2 t01 = xl01 + xr01, t23 = xl23 + xr23;
  f32x2 l01 = __builtin_elementwise_max(t01, t01 * NEG);
  f32x2 l23 = __builtin_elementwise_max(t23, t23 * NEG);
  f32x2 ps = l01 * a01 + l23 * a23;
  float p = ps.x + ps.y;
  p += __shfl_xor(p, 1, 8);
  p += __shfl_xor(p, 2, 8);
  p += __shfl_xor(p, 4, 8);
  float m = p, ssum = 1.f;
  f32x2 O01 = xl01, O23 = xl23;

  int e = offs[i], end = offs[i + 1];
  for (; e + 1 < end; e += 2) {
    int j0 = csr[e], j1 = csr[e + 1];
    uint2 u0 = rows[(size_t)j0 * 128 + lane];
    uint2 u1 = rows[(size_t)j1 * 128 + lane];
    f32x2 x001 = bfpair(u0.x), x023 = bfpair(u0.y);
    f32x2 x101 = bfpair(u1.x), x123 = bfpair(u1.y);
    f32x2 q01 = x001 + xr01, q23 = x023 + xr23;
    f32x2 r01 = x101 + xr01, r23 = x123 + xr23;
    f32x2 g01 = __builtin_elementwise_max(q01, q01 * NEG);
    f32x2 g23 = __builtin_elementwise_max(q23, q23 * NEG);
    f32x2 k01 = __builtin_elementwise_max(r01, r01 * NEG);
    f32x2 k23 = __builtin_elementwise_max(r23, r23 * NEG);
    f32x2 s0v = g01 * a01 + g23 * a23;
    f32x2 s1v = k01 * a01 + k23 * a23;
    float p0 = s0v.x + s0v.y;
    float p1 = s1v.x + s1v.y;
    p0 += __shfl_xor(p0, 1, 8);
    p1 += __shfl_xor(p1, 1, 8);
    p0 += __shfl_xor(p0, 2, 8);
    p1 += __shfl_xor(p1, 2, 8);
    p0 += __shfl_xor(p0, 4, 8);
    p1 += __shfl_xor(p1, 4, 8);
    float mx = fmaxf(p0, p1);
    if (!__all(mx <= m + 8.f)) {        // defer-max (T13)
      float mn = fmaxf(m, mx);
      float sc = __expf(m - mn);
      O01 *= sc; O23 *= sc; ssum *= sc; m = mn;
    }
    float w0 = __expf(p0 - m), w1 = __expf(p1 - m);
    O01 += w0 * x001 + w1 * x101;
    O23 += w0 * x023 + w1 * x123;
    ssum += w0 + w1;
  }
  if (e < end) {
    int j0 = csr[e];
    uint2 u0 = rows[(size_t)j0 * 128 + lane];
    f32x2 x001 = bfpair(u0.x), x023 = bfpair(u0.y);
    f32x2 q01 = x001 + xr01, q23 = x023 + xr23;
    f32x2 g01 = __builtin_elementwise_max(q01, q01 * NEG);
    f32x2 g23 = __builtin_elementwise_max(q23, q23 * NEG);
    f32x2 s0v = g01 * a01 + g23 * a23;
    float p0 = s0v.x + s0v.y;
    p0 += __shfl_xor(p0, 1, 8);
    p0 += __shfl_xor(p0, 2, 8);
    p0 += __shfl_xor(p0, 4, 8);
    if (!__all(p0 <= m + 8.f)) {
      float mn = fmaxf(m, p0);
      float sc = __expf(m - mn);
      O01 *= sc; O23 *= sc; ssum *= sc; m = mn;
    }
    float w0 = __expf(p0 - m);
    O01 += w0 * x001;
    O23 += w0 * x023;
    ssum += w0;
  }
  float inv = 1.f / (ssum + 1e-16f);
  float4 b4 = ((const float4*)bias)[lane];
  float h0 = O01.x * inv + b4.x;
  float h1 = O01.y * inv + b4.y;
  float h2 = O23.x * inv + b4.z;
  float h3 = O23.y * inv + b4.w;
  h0 = h0 > 0.f ? h0 : (__expf(h0) - 1.f);
  h1 = h1 > 0.f ? h1 : (__expf(h1) - 1.f);
  h2 = h2 > 0.f ? h2 : (__expf(h2) - 1.f);
  h3 = h3 > 0.f ? h3 : (__expf(h3) - 1.f);
  ushort4 o;
  o.x = f2bf(h0); o.y = f2bf(h1); o.z = f2bf(h2); o.w = f2bf(h3);
  ((ushort4*)(h + (size_t)i * 256))[lane] = o;
}

// ---------------- fused GATv2 layer 2 (H=1, Fo=16) ----------------
__global__ __launch_bounds__(256) void gat2_kernel(const float* __restrict__ xlr2,
    const float* __restrict__ att, const float* __restrict__ b2,
    const int* __restrict__ offs, const int* __restrict__ csr,
    float* __restrict__ yout, int N) {
  int grp = threadIdx.x >> 4, c = threadIdx.x & 15;
  int i = blockIdx.x * 16 + grp;
  if (i >= N) return;
  float xli = xlr2[(size_t)i * 32 + c];
  float xri = xlr2[(size_t)i * 32 + 16 + c];
  float a = att[c];
  float v = xli + xri; v = fmaxf(v, NEG * v);
  float p = v * a;
#pragma unroll
  for (int o = 8; o >= 1; o >>= 1) p += __shfl_xor(p, o, 16);
  float m = p, ssum = 1.0f, O = xli;
  int e = offs[i], end = offs[i + 1];
  for (; e < end; e++) {
    int j = csr[e];
    float xlj = xlr2[(size_t)j * 32 + c];
    float vv = xlj + xri; vv = fmaxf(vv, NEG * vv);
    float pp = vv * a;
#pragma unroll
    for (int o = 8; o >= 1; o >>= 1) pp += __shfl_xor(pp, o, 16);
    float mn = fmaxf(m, pp);
    float sc = __expf(m - mn);
    float wv = __expf(pp - mn);
    O = fmaf(O, sc, wv * xlj);
    ssum = fmaf(ssum, sc, wv);
    m = mn;
  }
  yout[(size_t)i * C2 + c] = O / (ssum + 1e-16f) + b2[c];
}

// ---------------- finalize ----------------
__global__ __launch_bounds__(256) void finalize_kernel(const float* __restrict__ y,
    const float* __restrict__ z, float* __restrict__ out, int N) {
  int grp = threadIdx.x >> 4, c = threadIdx.x & 15;
  int i = blockIdx.x * 16 + grp;
  if (i >= N) return;
  float yv = y[(size_t)i * C2 + c];
  float zv = z[(size_t)i * C2 + c];
  float my = yv;
#pragma unroll
  for (int o = 8; o >= 1; o >>= 1) my = fmaxf(my, __shfl_xor(my, o, 16));
  float sy = __expf(yv - my);
#pragma unroll
  for (int o = 8; o >= 1; o >>= 1) sy += __shfl_xor(sy, o, 16);
  float lpy = yv - my - __logf(sy);
  float mz = zv;
#pragma unroll
  for (int o = 8; o >= 1; o >>= 1) mz = fmaxf(mz, __shfl_xor(mz, o, 16));
  float sz = __expf(zv - mz);
#pragma unroll
  for (int o = 8; o >= 1; o >>= 1) sz += __shfl_xor(sz, o, 16);
  float lpz = zv - mz - __logf(sz);
  float dot = yv * zv, ny2 = yv * yv, nz2 = zv * zv;
#pragma unroll
  for (int o = 8; o >= 1; o >>= 1) {
    dot += __shfl_xor(dot, o, 16);
    ny2 += __shfl_xor(ny2, o, 16);
    nz2 += __shfl_xor(nz2, o, 16);
  }
  float ny = fmaxf(sqrtf(ny2), 1e-8f);
  float nz = fmaxf(sqrtf(nz2), 1e-8f);
  float cosv = dot / (ny * nz);
  size_t o1 = (size_t)N * C2;
  size_t o2 = o1 + N;
  size_t o3 = o2 + (size_t)N * C2;
  size_t o4 = o3 + (size_t)N * C2;
  size_t idx = (size_t)i * C2 + c;
  out[idx] = lpy;
  if (c == 0) out[o1 + i] = 1.0f - cosv;
  out[o2 + idx] = lpz;
  out[o3 + idx] = lpy;
  out[o4 + idx] = lpy;
}

extern "C" void kernel_launch(void* const* d_in, const int* in_sizes, int n_in,
                              void* d_out, int out_size, void* d_ws, size_t ws_size,
                              hipStream_t stream) {
  const float* x1   = (const float*)d_in[0];
  const int*   ei1  = (const int*)d_in[1];
  const float* x2   = (const float*)d_in[2];
  const int*   ei2  = (const int*)d_in[3];
  const float* W1l  = (const float*)d_in[4];
  const float* W1r  = (const float*)d_in[5];
  const float* att1 = (const float*)d_in[6];
  const float* b1   = (const float*)d_in[7];
  const float* W2l  = (const float*)d_in[8];
  const float* W2r  = (const float*)d_in[9];
  const float* att2 = (const float*)d_in[10];
  const float* b2   = (const float*)d_in[11];
  const int N = in_sizes[0] / FIN;
  const int E = in_sizes[1] / 2;
  float* out = (float*)d_out;

  char* w = (char*)d_ws;
  size_t off = 0;
  auto carve = [&](size_t bytes) -> void* {
    void* p = w + off;
    off += (bytes + 255) & ~(size_t)255;
    return p;
  };
  unsigned short* xlr_b = (unsigned short*)carve((size_t)N * 512 * 2);
  unsigned short* h     = (unsigned short*)carve((size_t)N * 256 * 2);
  unsigned short* xcvt  = h;   // alias: xcvt dead before gat1 writes h
  unsigned short* Wt    = (unsigned short*)carve(512 * 256 * 2);
  unsigned short* Wt2   = (unsigned short*)carve(32 * 256 * 2);
  float* xlr2 = (float*)carve((size_t)N * 32 * 4);
  float* yb   = (float*)carve((size_t)N * 16 * 4);
  float* zb   = (float*)carve((size_t)N * 16 * 4);
  int* deg  = (int*)carve((size_t)N * 4);
  int* cnt  = (int*)carve((size_t)N * 4);
  int* offs = (int*)carve((size_t)(N + 1) * 4);
  int* csr  = (int*)carve((size_t)E * 4);
  int* partials = (int*)carve(64 * 4);
  int* carries  = (int*)carve(64 * 4);
  (void)ws_size; (void)n_in; (void)out_size;

  // memset must span deg..cnt INCLUDING carve padding (R3 bug: 192B of cnt unzeroed)
  const size_t deg_cnt_bytes = (size_t)((char*)cnt - (char*)deg) + (size_t)N * 4;

  const int NB = (N + 1023) / 1024;   // 49 for N=50000 (<=64 required)

  cvt_w_kernel<<<512, 256, 0, stream>>>(W1l, W1r, Wt);
  cvt_w2_kernel<<<32, 256, 0, stream>>>(W2l, W2r, Wt2);

  for (int g = 0; g < 2; g++) {
    const float* x  = g ? x2 : x1;
    const int*   ei = g ? ei2 : ei1;
    float* yout = g ? zb : yb;
    const int* srcp = ei;
    const int* dstp = ei + E;

    hipMemsetAsync(deg, 0, deg_cnt_bytes, stream);   // deg + pad + cnt
    deg_kernel<<<(E + 255) / 256, 256, 0, stream>>>(dstp, deg, E);
    scan_part_kernel<<<NB, 1024, 0, stream>>>(deg, offs, partials, N);
    scan_carry_kernel<<<1, 64, 0, stream>>>(partials, carries, offs, NB, N);
    if (NB > 1) scan_add_kernel<<<NB - 1, 1024, 0, stream>>>(offs, carries, N);
    fill_kernel<<<(E + 255) / 256, 256, 0, stream>>>(srcp, dstp, offs, cnt, csr, E);

    cvt_x_kernel<<<(N * FIN / 4 + 255) / 256, 256, 0, stream>>>(x, xcvt, N * FIN / 4);
    dim3 gg((N + 127) / 128, 4);
    gemm_mfma_kernel<<<gg, 256, 0, stream>>>(xcvt, Wt, xlr_b, N);
    gat1_kernel<<<(N + 3) / 4, 256, 0, stream>>>(xlr_b, att1, b1, offs, csr, h, N);
    gemm2_mfma_kernel<<<(N + 255) / 256, 256, 0, stream>>>(h, Wt2, xlr2, N);
    gat2_kernel<<<(N + 15) / 16, 256, 0, stream>>>(xlr2, att2, b2, offs, csr, yout, N);
  }
  finalize_kernel<<<(N + 15) / 16, 256, 0, stream>>>(yb, zb, out, N);
}

// Round 5
// 516.736 us; speedup vs baseline: 2.9335x; 1.0793x over previous
//
#include <hip/hip_runtime.h>
#include <hip/hip_bf16.h>
#include <math.h>

#define FIN 256
#define F1  256   // H1*HID = 8*32
#define C2  16
#define NEG 0.2f

typedef short bf16x8 __attribute__((ext_vector_type(8)));
typedef float f32x4v __attribute__((ext_vector_type(4)));
typedef float f32x2 __attribute__((ext_vector_type(2)));

__device__ __forceinline__ float bf2f(unsigned short u) {
  union { float f; unsigned int i; } c; c.i = ((unsigned int)u) << 16; return c.f;
}
__device__ __forceinline__ unsigned short f2bf(float f) {
  __hip_bfloat16 b = __float2bfloat16(f);
  return *(unsigned short*)&b;
}
// two bf16 packed in a u32 -> two f32 (x = low half, y = high half)
__device__ __forceinline__ f32x2 bfpair(unsigned int u) {
  union { float f; unsigned int i; } lo, hi;
  lo.i = u << 16;
  hi.i = u & 0xffff0000u;
  f32x2 r; r.x = lo.f; r.y = hi.f; return r;
}

// ---------------- CSR build ----------------
__global__ __launch_bounds__(256) void deg_kernel(const int* __restrict__ dst,
                                                  int* __restrict__ deg, int E) {
  int e = blockIdx.x * blockDim.x + threadIdx.x;
  if (e < E) atomicAdd(&deg[dst[e]], 1);
}

__global__ __launch_bounds__(1024) void scan_part_kernel(const int* __restrict__ deg,
    int* __restrict__ offs, int* __restrict__ partials, int n) {
  __shared__ int wsum[16], wpref[16];
  int tid = threadIdx.x, lane = tid & 63, wid = tid >> 6;
  int idx = blockIdx.x * 1024 + tid;
  int v = (idx < n) ? deg[idx] : 0;
  int s = v;
#pragma unroll
  for (int o = 1; o < 64; o <<= 1) {
    int t = __shfl_up(s, o, 64);
    if (lane >= o) s += t;
  }
  if (lane == 63) wsum[wid] = s;
  __syncthreads();
  if (tid < 16) {
    int t = wsum[tid];
    int ss = t;
#pragma unroll
    for (int o = 1; o < 16; o <<= 1) {
      int u = __shfl_up(ss, o, 16);
      if (tid >= o) ss += u;
    }
    wpref[tid] = ss - t;
    if (tid == 15) partials[blockIdx.x] = ss;
  }
  __syncthreads();
  if (idx < n) offs[idx] = wpref[wid] + s - v;
}

__global__ __launch_bounds__(64) void scan_carry_kernel(int* __restrict__ partials,
    int* __restrict__ carries, int* __restrict__ offs, int nb, int n) {
  int tid = threadIdx.x;
  int v = (tid < nb) ? partials[tid] : 0;
  int s = v;
#pragma unroll
  for (int o = 1; o < 64; o <<= 1) {
    int t = __shfl_up(s, o, 64);
    if (tid >= o) s += t;
  }
  if (tid < nb) carries[tid] = s - v;
  if (tid == 63) offs[n] = s;
}

__global__ __launch_bounds__(1024) void scan_add_kernel(int* __restrict__ offs,
    const int* __restrict__ carries, int n) {
  int b = blockIdx.x + 1;
  int idx = b * 1024 + threadIdx.x;
  if (idx < n) offs[idx] += carries[b];
}

__global__ __launch_bounds__(256) void fill_kernel(const int* __restrict__ src,
    const int* __restrict__ dst, const int* __restrict__ offs,
    int* __restrict__ cnt, int* __restrict__ csr, int E) {
  int e = blockIdx.x * blockDim.x + threadIdx.x;
  if (e < E) {
    int d = dst[e];
    int pos = offs[d] + atomicAdd(&cnt[d], 1);
    csr[pos] = src[e];
  }
}

// ---------------- weight converts (tiny, once) ----------------
__global__ __launch_bounds__(256) void cvt_w_kernel(const float* __restrict__ Wl,
    const float* __restrict__ Wr, unsigned short* __restrict__ Wt) {
  int n = blockIdx.x;
  int k = threadIdx.x;
  float v = (n < 256) ? Wl[k * 256 + n] : Wr[k * 256 + (n - 256)];
  Wt[n * 256 + k] = f2bf(v);
}

__global__ __launch_bounds__(256) void cvt_w2_kernel(const float* __restrict__ Wl,
    const float* __restrict__ Wr, unsigned short* __restrict__ Wt2) {
  int c = blockIdx.x;
  int k = threadIdx.x;
  float v = (c < 16) ? Wl[k * 16 + c] : Wr[k * 16 + (c - 16)];
  Wt2[c * 256 + k] = f2bf(v);
}

// ---------------- MFMA GEMM (fused f32->bf16 A convert): C[M,512](bf16) ----------------
#define LDT 72
__global__ __launch_bounds__(256) void gemm_mfma_kernel(
    const float* __restrict__ A, const unsigned short* __restrict__ Bt,
    unsigned short* __restrict__ C, int M) {
  __shared__ __align__(16) unsigned short As[128 * LDT];
  __shared__ __align__(16) unsigned short Bs[128 * LDT];
  int tid = threadIdx.x;
  int row0 = blockIdx.x * 128;
  int col0 = blockIdx.y * 128;
  int wid = tid >> 6, lane = tid & 63;
  int wr = wid >> 1, wc = wid & 1;
  int r16 = lane & 15, kb = (lane >> 4) * 8;

  f32x4v acc[4][4];
#pragma unroll
  for (int m = 0; m < 4; m++)
#pragma unroll
    for (int n = 0; n < 4; n++)
#pragma unroll
      for (int q = 0; q < 4; q++) acc[m][n][q] = 0.f;

  for (int k0 = 0; k0 < 256; k0 += 64) {
#pragma unroll
    for (int it = 0; it < 4; it++) {
      int c = tid + it * 256;         // 0..1023
      int r = c >> 3;
      int ko = (c & 7) * 8;
      int gr = row0 + r;
      float4 a0 = make_float4(0.f, 0.f, 0.f, 0.f);
      float4 a1 = make_float4(0.f, 0.f, 0.f, 0.f);
      if (gr < M) {
        a0 = *(const float4*)&A[(size_t)gr * 256 + k0 + ko];
        a1 = *(const float4*)&A[(size_t)gr * 256 + k0 + ko + 4];
      }
      ushort4 lo, hi;
      lo.x = f2bf(a0.x); lo.y = f2bf(a0.y); lo.z = f2bf(a0.z); lo.w = f2bf(a0.w);
      hi.x = f2bf(a1.x); hi.y = f2bf(a1.y); hi.z = f2bf(a1.z); hi.w = f2bf(a1.w);
      *(ushort4*)&As[r * LDT + ko] = lo;
      *(ushort4*)&As[r * LDT + ko + 4] = hi;
      int4 bv = *(const int4*)&Bt[(size_t)(col0 + r) * 256 + k0 + ko];
      *(int4*)&Bs[r * LDT + ko] = bv;
    }
    __syncthreads();
#pragma unroll
    for (int kk = 0; kk < 64; kk += 32) {
      bf16x8 af[4], bfr[4];
#pragma unroll
      for (int m = 0; m < 4; m++)
        af[m] = *(const bf16x8*)&As[(wr * 64 + m * 16 + r16) * LDT + kk + kb];
#pragma unroll
      for (int n = 0; n < 4; n++)
        bfr[n] = *(const bf16x8*)&Bs[(wc * 64 + n * 16 + r16) * LDT + kk + kb];
#pragma unroll
      for (int m = 0; m < 4; m++)
#pragma unroll
        for (int n = 0; n < 4; n++)
          acc[m][n] = __builtin_amdgcn_mfma_f32_16x16x32_bf16(af[m], bfr[n], acc[m][n], 0, 0, 0);
    }
    __syncthreads();
  }
  int rq = (lane >> 4) * 4;
#pragma unroll
  for (int m = 0; m < 4; m++) {
#pragma unroll
    for (int n = 0; n < 4; n++) {
#pragma unroll
      for (int q = 0; q < 4; q++) {
        int gr = row0 + wr * 64 + m * 16 + rq + q;
        if (gr < M) {
          int gc = col0 + wc * 64 + n * 16 + r16;
          C[(size_t)gr * 512 + gc] = f2bf(acc[m][n][q]);
        }
      }
    }
  }
}

// ---------------- layer-2 MFMA GEMM: C[M,32](bf16) = h[M,256](bf16) @ Wt2^T ----------------
#define LDB2 264
__global__ __launch_bounds__(256) void gemm2_mfma_kernel(
    const unsigned short* __restrict__ A, const unsigned short* __restrict__ Bt,
    unsigned short* __restrict__ C, int M) {
  __shared__ __align__(16) unsigned short As[256 * LDT];
  __shared__ __align__(16) unsigned short Bs[32 * LDB2];
  int tid = threadIdx.x;
  int row0 = blockIdx.x * 256;
  int wid = tid >> 6, lane = tid & 63;
  int r16 = lane & 15, kb = (lane >> 4) * 8, rq = (lane >> 4) * 4;

#pragma unroll
  for (int it = 0; it < 4; it++) {
    int g = tid + it * 256;           // 0..1023 granules of B
    int r = g >> 5;
    int ko = (g & 31) * 8;
    *(int4*)&Bs[r * LDB2 + ko] = *(const int4*)&Bt[r * 256 + ko];
  }

  f32x4v acc[4][2];
#pragma unroll
  for (int m = 0; m < 4; m++)
#pragma unroll
    for (int n = 0; n < 2; n++)
#pragma unroll
      for (int q = 0; q < 4; q++) acc[m][n][q] = 0.f;

  for (int k0 = 0; k0 < 256; k0 += 64) {
#pragma unroll
    for (int it = 0; it < 8; it++) {
      int g = tid + it * 256;         // 0..2047
      int r = g >> 3;
      int ko = (g & 7) * 8;
      int gr = row0 + r;
      int4 av = make_int4(0, 0, 0, 0);
      if (gr < M) av = *(const int4*)&A[(size_t)gr * 256 + k0 + ko];
      *(int4*)&As[r * LDT + ko] = av;
    }
    __syncthreads();
#pragma unroll
    for (int kk = 0; kk < 64; kk += 32) {
      bf16x8 af[4], bfr[2];
#pragma unroll
      for (int m = 0; m < 4; m++)
        af[m] = *(const bf16x8*)&As[(wid * 64 + m * 16 + r16) * LDT + kk + kb];
#pragma unroll
      for (int n = 0; n < 2; n++)
        bfr[n] = *(const bf16x8*)&Bs[(n * 16 + r16) * LDB2 + k0 + kk + kb];
#pragma unroll
      for (int m = 0; m < 4; m++)
#pragma unroll
        for (int n = 0; n < 2; n++)
          acc[m][n] = __builtin_amdgcn_mfma_f32_16x16x32_bf16(af[m], bfr[n], acc[m][n], 0, 0, 0);
    }
    __syncthreads();
  }
#pragma unroll
  for (int m = 0; m < 4; m++) {
#pragma unroll
    for (int n = 0; n < 2; n++) {
#pragma unroll
      for (int q = 0; q < 4; q++) {
        int gr = row0 + wid * 64 + m * 16 + rq + q;
        if (gr < M) C[(size_t)gr * 32 + n * 16 + r16] = f2bf(acc[m][n][q]);
      }
    }
  }
}

// ---------------- fused GATv2 layer 1 (1 wave/node, prefetch-pipelined, defer-max) ----------------
__global__ __launch_bounds__(256) void gat1_kernel(const unsigned short* __restrict__ xlr,
    const float* __restrict__ att, const float* __restrict__ bias,
    const int* __restrict__ offs, const int* __restrict__ csr,
    unsigned short* __restrict__ h, int N) {
  int w = threadIdx.x >> 6, lane = threadIdx.x & 63;
  int i = blockIdx.x * 4 + w;
  if (i >= N) return;
  const uint2* rows = (const uint2*)xlr;   // 8B granule = 4 bf16
  uint2 ul = rows[(size_t)i * 128 + lane];
  uint2 ur = rows[(size_t)i * 128 + 64 + lane];
  f32x2 xl01 = bfpair(ul.x), xl23 = bfpair(ul.y);
  f32x2 xr01 = bfpair(ur.x), xr23 = bfpair(ur.y);
  float4 a4 = ((const float4*)att)[lane];
  f32x2 a01; a01.x = a4.x; a01.y = a4.y;
  f32x2 a23; a23.x = a4.z; a23.y = a4.w;

  // self-loop
  f32x2 t01 = xl01 + xr01, t23 = xl23 + xr23;
  f32x2 l01 = __builtin_elementwise_max(t01, t01 * NEG);
  f32x2 l23 = __builtin_elementwise_max(t23, t23 * NEG);
  f32x2 ps = l01 * a01 + l23 * a23;
  float p = ps.x + ps.y;
  p += __shfl_xor(p, 1, 8);
  p += __shfl_xor(p, 2, 8);
  p += __shfl_xor(p, 4, 8);
  float m = p, ssum = 1.f;
  f32x2 O01 = xl01, O23 = xl23;

  int e = offs[i], end = offs[i + 1];
  int rem = end - e;
  // prime the pipeline: current pair in (u0,u1)
  int j0 = (rem >= 1) ? csr[e] : i;
  int j1 = (rem >= 2) ? csr[e + 1] : i;
  uint2 u0 = rows[(size_t)j0 * 128 + lane];
  uint2 u1 = rows[(size_t)j1 * 128 + lane];

  while (rem >= 2) {
    int nrem = rem - 2;
    // prefetch next pair (safe index i when absent)
    int nj0 = (nrem >= 1) ? csr[e + 2] : i;
    int nj1 = (nrem >= 2) ? csr[e + 3] : i;
    uint2 v0 = rows[(size_t)nj0 * 128 + lane];
    uint2 v1 = rows[(size_t)nj1 * 128 + lane];
    // compute current pair
    f32x2 x001 = bfpair(u0.x), x023 = bfpair(u0.y);
    f32x2 x101 = bfpair(u1.x), x123 = bfpair(u1.y);
    f32x2 q01 = x001 + xr01, q23 = x023 + xr23;
    f32x2 r01 = x101 + xr01, r23 = x123 + xr23;
    f32x2 g01 = __builtin_elementwise_max(q01, q01 * NEG);
    f32x2 g23 = __builtin_elementwise_max(q23, q23 * NEG);
    f32x2 k01 = __builtin_elementwise_max(r01, r01 * NEG);
    f32x2 k23 = __builtin_elementwise_max(r23, r23 * NEG);
    f32x2 s0v = g01 * a01 + g23 * a23;
    f32x2 s1v = k01 * a01 + k23 * a23;
    float p0 = s0v.x + s0v.y;
    float p1 = s1v.x + s1v.y;
    p0 += __shfl_xor(p0, 1, 8);
    p1 += __shfl_xor(p1, 1, 8);
    p0 += __shfl_xor(p0, 2, 8);
    p1 += __shfl_xor(p1, 2, 8);
    p0 += __shfl_xor(p0, 4, 8);
    p1 += __shfl_xor(p1, 4, 8);
    float mx = fmaxf(p0, p1);
    if (!__all(mx <= m + 8.f)) {        // defer-max (T13)
      float mn = fmaxf(m, mx);
      float sc = __expf(m - mn);
      O01 *= sc; O23 *= sc; ssum *= sc; m = mn;
    }
    float w0 = __expf(p0 - m), w1 = __expf(p1 - m);
    O01 += w0 * x001 + w1 * x101;
    O23 += w0 * x023 + w1 * x123;
    ssum += w0 + w1;
    u0 = v0; u1 = v1; e += 2; rem = nrem;
  }
  if (rem == 1) {
    f32x2 x001 = bfpair(u0.x), x023 = bfpair(u0.y);
    f32x2 q01 = x001 + xr01, q23 = x023 + xr23;
    f32x2 g01 = __builtin_elementwise_max(q01, q01 * NEG);
    f32x2 g23 = __builtin_elementwise_max(q23, q23 * NEG);
    f32x2 s0v = g01 * a01 + g23 * a23;
    float p0 = s0v.x + s0v.y;
    p0 += __shfl_xor(p0, 1, 8);
    p0 += __shfl_xor(p0, 2, 8);
    p0 += __shfl_xor(p0, 4, 8);
    if (!__all(p0 <= m + 8.f)) {
      float mn = fmaxf(m, p0);
      float sc = __expf(m - mn);
      O01 *= sc; O23 *= sc; ssum *= sc; m = mn;
    }
    float w0 = __expf(p0 - m);
    O01 += w0 * x001;
    O23 += w0 * x023;
    ssum += w0;
  }
  float inv = 1.f / (ssum + 1e-16f);
  float4 b4 = ((const float4*)bias)[lane];
  float h0 = O01.x * inv + b4.x;
  float h1 = O01.y * inv + b4.y;
  float h2 = O23.x * inv + b4.z;
  float h3 = O23.y * inv + b4.w;
  h0 = h0 > 0.f ? h0 : (__expf(h0) - 1.f);
  h1 = h1 > 0.f ? h1 : (__expf(h1) - 1.f);
  h2 = h2 > 0.f ? h2 : (__expf(h2) - 1.f);
  h3 = h3 > 0.f ? h3 : (__expf(h3) - 1.f);
  ushort4 o;
  o.x = f2bf(h0); o.y = f2bf(h1); o.z = f2bf(h2); o.w = f2bf(h3);
  ((ushort4*)(h + (size_t)i * 256))[lane] = o;
}

// ---------------- fused GATv2 layer 2 (bf16 in, prefetch-pipelined, defer-max) ----------------
// Note: __all is wave-wide over 4 independent 16-lane groups; groups not needing
// rescale compute mn==m, sc=1 -> harmless no-op. Correct, occasionally redundant.
__global__ __launch_bounds__(256) void gat2_kernel(const unsigned short* __restrict__ xlr2,
    const float* __restrict__ att, const float* __restrict__ b2,
    const int* __restrict__ offs, const int* __restrict__ csr,
    float* __restrict__ yout, int N) {
  int grp = threadIdx.x >> 4, c = threadIdx.x & 15;
  int i = blockIdx.x * 16 + grp;
  if (i >= N) return;
  float xli = bf2f(xlr2[(size_t)i * 32 + c]);
  float xri = bf2f(xlr2[(size_t)i * 32 + 16 + c]);
  float a = att[c];
  float v = xli + xri; v = fmaxf(v, NEG * v);
  float p = v * a;
#pragma unroll
  for (int o = 8; o >= 1; o >>= 1) p += __shfl_xor(p, o, 16);
  float m = p, ssum = 1.0f, O = xli;

  int e = offs[i], end = offs[i + 1];
  int rem = end - e;
  int j0 = (rem >= 1) ? csr[e] : i;
  int j1 = (rem >= 2) ? csr[e + 1] : i;
  float x0 = bf2f(xlr2[(size_t)j0 * 32 + c]);
  float x1 = bf2f(xlr2[(size_t)j1 * 32 + c]);

  while (rem >= 2) {
    int nrem = rem - 2;
    int nj0 = (nrem >= 1) ? csr[e + 2] : i;
    int nj1 = (nrem >= 2) ? csr[e + 3] : i;
    float v0 = bf2f(xlr2[(size_t)nj0 * 32 + c]);
    float v1 = bf2f(xlr2[(size_t)nj1 * 32 + c]);
    float q0 = x0 + xri; q0 = fmaxf(q0, NEG * q0);
    float q1 = x1 + xri; q1 = fmaxf(q1, NEG * q1);
    float p0 = q0 * a, p1 = q1 * a;
#pragma unroll
    for (int o = 8; o >= 1; o >>= 1) {
      p0 += __shfl_xor(p0, o, 16);
      p1 += __shfl_xor(p1, o, 16);
    }
    float mx = fmaxf(p0, p1);
    if (!__all(mx <= m + 8.f)) {
      float mn = fmaxf(m, mx);
      float sc = __expf(m - mn);
      O *= sc; ssum *= sc; m = mn;
    }
    float w0 = __expf(p0 - m), w1 = __expf(p1 - m);
    O += w0 * x0 + w1 * x1;
    ssum += w0 + w1;
    x0 = v0; x1 = v1; e += 2; rem = nrem;
  }
  if (rem == 1) {
    float q0 = x0 + xri; q0 = fmaxf(q0, NEG * q0);
    float p0 = q0 * a;
#pragma unroll
    for (int o = 8; o >= 1; o >>= 1) p0 += __shfl_xor(p0, o, 16);
    if (!__all(p0 <= m + 8.f)) {
      float mn = fmaxf(m, p0);
      float sc = __expf(m - mn);
      O *= sc; ssum *= sc; m = mn;
    }
    float w0 = __expf(p0 - m);
    O += w0 * x0;
    ssum += w0;
  }
  yout[(size_t)i * C2 + c] = O / (ssum + 1e-16f) + b2[c];
}

// ---------------- finalize ----------------
__global__ __launch_bounds__(256) void finalize_kernel(const float* __restrict__ y,
    const float* __restrict__ z, float* __restrict__ out, int N) {
  int grp = threadIdx.x >> 4, c = threadIdx.x & 15;
  int i = blockIdx.x * 16 + grp;
  if (i >= N) return;
  float yv = y[(size_t)i * C2 + c];
  float zv = z[(size_t)i * C2 + c];
  float my = yv;
#pragma unroll
  for (int o = 8; o >= 1; o >>= 1) my = fmaxf(my, __shfl_xor(my, o, 16));
  float sy = __expf(yv - my);
#pragma unroll
  for (int o = 8; o >= 1; o >>= 1) sy += __shfl_xor(sy, o, 16);
  float lpy = yv - my - __logf(sy);
  float mz = zv;
#pragma unroll
  for (int o = 8; o >= 1; o >>= 1) mz = fmaxf(mz, __shfl_xor(mz, o, 16));
  float sz = __expf(zv - mz);
#pragma unroll
  for (int o = 8; o >= 1; o >>= 1) sz += __shfl_xor(sz, o, 16);
  float lpz = zv - mz - __logf(sz);
  float dot = yv * zv, ny2 = yv * yv, nz2 = zv * zv;
#pragma unroll
  for (int o = 8; o >= 1; o >>= 1) {
    dot += __shfl_xor(dot, o, 16);
    ny2 += __shfl_xor(ny2, o, 16);
    nz2 += __shfl_xor(nz2, o, 16);
  }
  float ny = fmaxf(sqrtf(ny2), 1e-8f);
  float nz = fmaxf(sqrtf(nz2), 1e-8f);
  float cosv = dot / (ny * nz);
  size_t o1 = (size_t)N * C2;
  size_t o2 = o1 + N;
  size_t o3 = o2 + (size_t)N * C2;
  size_t o4 = o3 + (size_t)N * C2;
  size_t idx = (size_t)i * C2 + c;
  out[idx] = lpy;
  if (c == 0) out[o1 + i] = 1.0f - cosv;
  out[o2 + idx] = lpz;
  out[o3 + idx] = lpy;
  out[o4 + idx] = lpy;
}

extern "C" void kernel_launch(void* const* d_in, const int* in_sizes, int n_in,
                              void* d_out, int out_size, void* d_ws, size_t ws_size,
                              hipStream_t stream) {
  const float* x1   = (const float*)d_in[0];
  const int*   ei1  = (const int*)d_in[1];
  const float* x2   = (const float*)d_in[2];
  const int*   ei2  = (const int*)d_in[3];
  const float* W1l  = (const float*)d_in[4];
  const float* W1r  = (const float*)d_in[5];
  const float* att1 = (const float*)d_in[6];
  const float* b1   = (const float*)d_in[7];
  const float* W2l  = (const float*)d_in[8];
  const float* W2r  = (const float*)d_in[9];
  const float* att2 = (const float*)d_in[10];
  const float* b2   = (const float*)d_in[11];
  const int N = in_sizes[0] / FIN;
  const int E = in_sizes[1] / 2;
  float* out = (float*)d_out;

  char* w = (char*)d_ws;
  size_t off = 0;
  auto carve = [&](size_t bytes) -> void* {
    void* p = w + off;
    off += (bytes + 255) & ~(size_t)255;
    return p;
  };
  unsigned short* xlr_b = (unsigned short*)carve((size_t)N * 512 * 2);
  unsigned short* h     = (unsigned short*)carve((size_t)N * 256 * 2);
  unsigned short* Wt    = (unsigned short*)carve(512 * 256 * 2);
  unsigned short* Wt2   = (unsigned short*)carve(32 * 256 * 2);
  unsigned short* xlr2b = (unsigned short*)carve((size_t)N * 32 * 2);
  float* yb   = (float*)carve((size_t)N * 16 * 4);
  float* zb   = (float*)carve((size_t)N * 16 * 4);
  int* deg  = (int*)carve((size_t)N * 4);
  int* cnt  = (int*)carve((size_t)N * 4);
  int* offs = (int*)carve((size_t)(N + 1) * 4);
  int* csr  = (int*)carve((size_t)E * 4);
  int* partials = (int*)carve(64 * 4);
  int* carries  = (int*)carve(64 * 4);
  (void)ws_size; (void)n_in; (void)out_size;

  // memset spans deg..cnt INCLUDING carve padding
  const size_t deg_cnt_bytes = (size_t)((char*)cnt - (char*)deg) + (size_t)N * 4;

  const int NB = (N + 1023) / 1024;   // 49 for N=50000 (<=64 required)

  cvt_w_kernel<<<512, 256, 0, stream>>>(W1l, W1r, Wt);
  cvt_w2_kernel<<<32, 256, 0, stream>>>(W2l, W2r, Wt2);

  for (int g = 0; g < 2; g++) {
    const float* x  = g ? x2 : x1;
    const int*   ei = g ? ei2 : ei1;
    float* yout = g ? zb : yb;
    const int* srcp = ei;
    const int* dstp = ei + E;

    hipMemsetAsync(deg, 0, deg_cnt_bytes, stream);
    deg_kernel<<<(E + 255) / 256, 256, 0, stream>>>(dstp, deg, E);
    scan_part_kernel<<<NB, 1024, 0, stream>>>(deg, offs, partials, N);
    scan_carry_kernel<<<1, 64, 0, stream>>>(partials, carries, offs, NB, N);
    if (NB > 1) scan_add_kernel<<<NB - 1, 1024, 0, stream>>>(offs, carries, N);
    fill_kernel<<<(E + 255) / 256, 256, 0, stream>>>(srcp, dstp, offs, cnt, csr, E);

    dim3 gg((N + 127) / 128, 4);
    gemm_mfma_kernel<<<gg, 256, 0, stream>>>(x, Wt, xlr_b, N);
    gat1_kernel<<<(N + 3) / 4, 256, 0, stream>>>(xlr_b, att1, b1, offs, csr, h, N);
    gemm2_mfma_kernel<<<(N + 255) / 256, 256, 0, stream>>>(h, Wt2, xlr2b, N);
    gat2_kernel<<<(N + 15) / 16, 256, 0, stream>>>(xlr2b, att2, b2, offs, csr, yout, N);
  }
  finalize_kernel<<<(N + 15) / 16, 256, 0, stream>>>(yb, zb, out, N);
}

// Round 6
// 483.642 us; speedup vs baseline: 3.1342x; 1.0684x over previous
//
#include <hip/hip_runtime.h>
#include <hip/hip_bf16.h>
#include <math.h>

#define FIN 256
#define F1  256   // H1*HID = 8*32
#define C2  16
#define NEG 0.2f

typedef short bf16x8 __attribute__((ext_vector_type(8)));
typedef float f32x4v __attribute__((ext_vector_type(4)));
typedef float f32x2 __attribute__((ext_vector_type(2)));

__device__ __forceinline__ float bf2f(unsigned short u) {
  union { float f; unsigned int i; } c; c.i = ((unsigned int)u) << 16; return c.f;
}
__device__ __forceinline__ unsigned short f2bf(float f) {
  __hip_bfloat16 b = __float2bfloat16(f);
  return *(unsigned short*)&b;
}
// two bf16 packed in a u32 -> two f32
__device__ __forceinline__ f32x2 bfpair(unsigned int u) {
  union { float f; unsigned int i; } lo, hi;
  lo.i = u << 16;
  hi.i = u & 0xffff0000u;
  f32x2 r; r.x = lo.f; r.y = hi.f; return r;
}

// ---------------- CSR build ----------------
__global__ __launch_bounds__(256) void deg_kernel(const int* __restrict__ dst,
                                                  int* __restrict__ deg, int E) {
  int e = blockIdx.x * blockDim.x + threadIdx.x;
  if (e < E) atomicAdd(&deg[dst[e]], 1);
}

__global__ __launch_bounds__(1024) void scan_part_kernel(const int* __restrict__ deg,
    int* __restrict__ offs, int* __restrict__ partials, int n) {
  __shared__ int wsum[16], wpref[16];
  int tid = threadIdx.x, lane = tid & 63, wid = tid >> 6;
  int idx = blockIdx.x * 1024 + tid;
  int v = (idx < n) ? deg[idx] : 0;
  int s = v;
#pragma unroll
  for (int o = 1; o < 64; o <<= 1) {
    int t = __shfl_up(s, o, 64);
    if (lane >= o) s += t;
  }
  if (lane == 63) wsum[wid] = s;
  __syncthreads();
  if (tid < 16) {
    int t = wsum[tid];
    int ss = t;
#pragma unroll
    for (int o = 1; o < 16; o <<= 1) {
      int u = __shfl_up(ss, o, 16);
      if (tid >= o) ss += u;
    }
    wpref[tid] = ss - t;
    if (tid == 15) partials[blockIdx.x] = ss;
  }
  __syncthreads();
  if (idx < n) offs[idx] = wpref[wid] + s - v;
}

// fused: re-scan partials in every block; block 0 writes total, blocks b>0 add carry
__global__ __launch_bounds__(1024) void scan_fix_kernel(int* __restrict__ offs,
    const int* __restrict__ partials, int nb, int n) {
  __shared__ int carry_s;
  int tid = threadIdx.x;
  int b = blockIdx.x;
  if (tid < 64) {
    int v = (tid < nb) ? partials[tid] : 0;
    int s = v;
#pragma unroll
    for (int o = 1; o < 64; o <<= 1) {
      int t = __shfl_up(s, o, 64);
      if (tid >= o) s += t;
    }
    if (b == 0) {
      if (tid == nb - 1) offs[n] = s;
    } else if (tid == b - 1) {
      carry_s = s;   // inclusive scan through b-1 == exclusive carry for chunk b
    }
  }
  __syncthreads();
  if (b > 0) {
    int idx = b * 1024 + tid;
    if (idx < n) offs[idx] += carry_s;
  }
}

__global__ __launch_bounds__(256) void fill_kernel(const int* __restrict__ src,
    const int* __restrict__ dst, const int* __restrict__ offs,
    int* __restrict__ cnt, int* __restrict__ csr, int E) {
  int e = blockIdx.x * blockDim.x + threadIdx.x;
  if (e < E) {
    int d = dst[e];
    int pos = offs[d] + atomicAdd(&cnt[d], 1);
    csr[pos] = src[e];
  }
}

// ---------------- weight converts (tiny, once) ----------------
__global__ __launch_bounds__(256) void cvt_w_kernel(const float* __restrict__ Wl,
    const float* __restrict__ Wr, unsigned short* __restrict__ Wt) {
  int n = blockIdx.x;
  int k = threadIdx.x;
  float v = (n < 256) ? Wl[k * 256 + n] : Wr[k * 256 + (n - 256)];
  Wt[n * 256 + k] = f2bf(v);
}

__global__ __launch_bounds__(256) void cvt_w2_kernel(const float* __restrict__ Wl,
    const float* __restrict__ Wr, unsigned short* __restrict__ Wt2) {
  int c = blockIdx.x;
  int k = threadIdx.x;
  float v = (c < 16) ? Wl[k * 16 + c] : Wr[k * 16 + (c - 16)];
  Wt2[c * 256 + k] = f2bf(v);
}

// ---------------- MFMA GEMM (fused f32->bf16 A convert, XCD-bijective swizzle) ----------------
#define LDT 72
__global__ __launch_bounds__(256) void gemm_mfma_kernel(
    const float* __restrict__ A, const unsigned short* __restrict__ Bt,
    unsigned short* __restrict__ C, int M) {
  __shared__ __align__(16) unsigned short As[128 * LDT];
  __shared__ __align__(16) unsigned short Bs[128 * LDT];
  int tid = threadIdx.x;
  // bijective XCD swizzle (m204): consecutive swz stay on one XCD; the 4 col-tiles
  // of a row-panel become adjacent so the 131KB A-panel is read once per XCD.
  int G = gridDim.x;
  int q = G >> 3, r = G & 7;
  int b = blockIdx.x;
  int xcd = b & 7, pos = b >> 3;
  int swz = (xcd < r) ? xcd * (q + 1) + pos : r * (q + 1) + (xcd - r) * q + pos;
  int row0 = (swz >> 2) * 128;
  int col0 = (swz & 3) * 128;
  int wid = tid >> 6, lane = tid & 63;
  int wr = wid >> 1, wc = wid & 1;
  int r16 = lane & 15, kb = (lane >> 4) * 8;

  f32x4v acc[4][4];
#pragma unroll
  for (int m = 0; m < 4; m++)
#pragma unroll
    for (int n = 0; n < 4; n++)
#pragma unroll
      for (int qq = 0; qq < 4; qq++) acc[m][n][qq] = 0.f;

  for (int k0 = 0; k0 < 256; k0 += 64) {
#pragma unroll
    for (int it = 0; it < 4; it++) {
      int c = tid + it * 256;         // 0..1023
      int rr = c >> 3;
      int ko = (c & 7) * 8;
      int gr = row0 + rr;
      float4 a0 = make_float4(0.f, 0.f, 0.f, 0.f);
      float4 a1 = make_float4(0.f, 0.f, 0.f, 0.f);
      if (gr < M) {
        a0 = *(const float4*)&A[(size_t)gr * 256 + k0 + ko];
        a1 = *(const float4*)&A[(size_t)gr * 256 + k0 + ko + 4];
      }
      ushort4 lo, hi;
      lo.x = f2bf(a0.x); lo.y = f2bf(a0.y); lo.z = f2bf(a0.z); lo.w = f2bf(a0.w);
      hi.x = f2bf(a1.x); hi.y = f2bf(a1.y); hi.z = f2bf(a1.z); hi.w = f2bf(a1.w);
      *(ushort4*)&As[rr * LDT + ko] = lo;
      *(ushort4*)&As[rr * LDT + ko + 4] = hi;
      int4 bv = *(const int4*)&Bt[(size_t)(col0 + rr) * 256 + k0 + ko];
      *(int4*)&Bs[rr * LDT + ko] = bv;
    }
    __syncthreads();
#pragma unroll
    for (int kk = 0; kk < 64; kk += 32) {
      bf16x8 af[4], bfr[4];
#pragma unroll
      for (int m = 0; m < 4; m++)
        af[m] = *(const bf16x8*)&As[(wr * 64 + m * 16 + r16) * LDT + kk + kb];
#pragma unroll
      for (int n = 0; n < 4; n++)
        bfr[n] = *(const bf16x8*)&Bs[(wc * 64 + n * 16 + r16) * LDT + kk + kb];
#pragma unroll
      for (int m = 0; m < 4; m++)
#pragma unroll
        for (int n = 0; n < 4; n++)
          acc[m][n] = __builtin_amdgcn_mfma_f32_16x16x32_bf16(af[m], bfr[n], acc[m][n], 0, 0, 0);
    }
    __syncthreads();
  }
  int rq = (lane >> 4) * 4;
#pragma unroll
  for (int m = 0; m < 4; m++) {
#pragma unroll
    for (int n = 0; n < 4; n++) {
#pragma unroll
      for (int qq = 0; qq < 4; qq++) {
        int gr = row0 + wr * 64 + m * 16 + rq + qq;
        if (gr < M) {
          int gc = col0 + wc * 64 + n * 16 + r16;
          C[(size_t)gr * 512 + gc] = f2bf(acc[m][n][qq]);
        }
      }
    }
  }
}

// ---------------- layer-2 MFMA GEMM: C[M,32](bf16) = h[M,256](bf16) @ Wt2^T ----------------
#define LDB2 264
__global__ __launch_bounds__(256) void gemm2_mfma_kernel(
    const unsigned short* __restrict__ A, const unsigned short* __restrict__ Bt,
    unsigned short* __restrict__ C, int M) {
  __shared__ __align__(16) unsigned short As[256 * LDT];
  __shared__ __align__(16) unsigned short Bs[32 * LDB2];
  int tid = threadIdx.x;
  int row0 = blockIdx.x * 256;
  int wid = tid >> 6, lane = tid & 63;
  int r16 = lane & 15, kb = (lane >> 4) * 8, rq = (lane >> 4) * 4;

#pragma unroll
  for (int it = 0; it < 4; it++) {
    int g = tid + it * 256;
    int rr = g >> 5;
    int ko = (g & 31) * 8;
    *(int4*)&Bs[rr * LDB2 + ko] = *(const int4*)&Bt[rr * 256 + ko];
  }

  f32x4v acc[4][2];
#pragma unroll
  for (int m = 0; m < 4; m++)
#pragma unroll
    for (int n = 0; n < 2; n++)
#pragma unroll
      for (int qq = 0; qq < 4; qq++) acc[m][n][qq] = 0.f;

  for (int k0 = 0; k0 < 256; k0 += 64) {
#pragma unroll
    for (int it = 0; it < 8; it++) {
      int g = tid + it * 256;
      int rr = g >> 3;
      int ko = (g & 7) * 8;
      int gr = row0 + rr;
      int4 av = make_int4(0, 0, 0, 0);
      if (gr < M) av = *(const int4*)&A[(size_t)gr * 256 + k0 + ko];
      *(int4*)&As[rr * LDT + ko] = av;
    }
    __syncthreads();
#pragma unroll
    for (int kk = 0; kk < 64; kk += 32) {
      bf16x8 af[4], bfr[2];
#pragma unroll
      for (int m = 0; m < 4; m++)
        af[m] = *(const bf16x8*)&As[(wid * 64 + m * 16 + r16) * LDT + kk + kb];
#pragma unroll
      for (int n = 0; n < 2; n++)
        bfr[n] = *(const bf16x8*)&Bs[(n * 16 + r16) * LDB2 + k0 + kk + kb];
#pragma unroll
      for (int m = 0; m < 4; m++)
#pragma unroll
        for (int n = 0; n < 2; n++)
          acc[m][n] = __builtin_amdgcn_mfma_f32_16x16x32_bf16(af[m], bfr[n], acc[m][n], 0, 0, 0);
    }
    __syncthreads();
  }
#pragma unroll
  for (int m = 0; m < 4; m++) {
#pragma unroll
    for (int n = 0; n < 2; n++) {
#pragma unroll
      for (int qq = 0; qq < 4; qq++) {
        int gr = row0 + wid * 64 + m * 16 + rq + qq;
        if (gr < M) C[(size_t)gr * 32 + n * 16 + r16] = f2bf(acc[m][n][qq]);
      }
    }
  }
}

// ---------------- fused GATv2 layer 1 (1 wave/node, depth-3 prefetch, scalar bases) ----------------
__global__ __launch_bounds__(256) void gat1_kernel(const unsigned short* __restrict__ xlr,
    const float* __restrict__ att, const float* __restrict__ bias,
    const int* __restrict__ offs, const int* __restrict__ csr,
    unsigned short* __restrict__ h, int N) {
  int w = threadIdx.x >> 6, lane = threadIdx.x & 63;
  int i = blockIdx.x * 4 + w;
  if (i >= N) return;
  i = __builtin_amdgcn_readfirstlane(i);   // wave-uniform -> scalar base math
  const uint2* rows = (const uint2*)xlr;
  const uint2* rowi = rows + (size_t)i * 128;
  uint2 ul = rowi[lane];
  uint2 ur = rowi[64 + lane];
  f32x2 xl01 = bfpair(ul.x), xl23 = bfpair(ul.y);
  f32x2 xr01 = bfpair(ur.x), xr23 = bfpair(ur.y);
  float4 a4 = ((const float4*)att)[lane];
  f32x2 a01; a01.x = a4.x; a01.y = a4.y;
  f32x2 a23; a23.x = a4.z; a23.y = a4.w;

  // self-loop
  f32x2 t01 = xl01 + xr01, t23 = xl23 + xr23;
  f32x2 l01 = __builtin_elementwise_max(t01, t01 * NEG);
  f32x2 l23 = __builtin_elementwise_max(t23, t23 * NEG);
  f32x2 ps = l01 * a01 + l23 * a23;
  float p = ps.x + ps.y;
  p += __shfl_xor(p, 1, 8);
  p += __shfl_xor(p, 2, 8);
  p += __shfl_xor(p, 4, 8);
  float m = p, ssum = 1.f;
  f32x2 O01 = xl01, O23 = xl23;

  int e = offs[i], end = offs[i + 1];
  int rem = end - e;

  // prime a 3-pair deep pipeline (dummy = self row, cached)
  int ja0 = __builtin_amdgcn_readfirstlane(rem > 0 ? csr[e + 0] : i);
  int ja1 = __builtin_amdgcn_readfirstlane(rem > 1 ? csr[e + 1] : i);
  uint2 ua0 = rows[(size_t)ja0 * 128 + lane];
  uint2 ua1 = rows[(size_t)ja1 * 128 + lane];
  int jb0 = __builtin_amdgcn_readfirstlane(rem > 2 ? csr[e + 2] : i);
  int jb1 = __builtin_amdgcn_readfirstlane(rem > 3 ? csr[e + 3] : i);
  uint2 ub0 = rows[(size_t)jb0 * 128 + lane];
  uint2 ub1 = rows[(size_t)jb1 * 128 + lane];
  int jc0 = __builtin_amdgcn_readfirstlane(rem > 4 ? csr[e + 4] : i);
  int jc1 = __builtin_amdgcn_readfirstlane(rem > 5 ? csr[e + 5] : i);
  uint2 uc0 = rows[(size_t)jc0 * 128 + lane];
  uint2 uc1 = rows[(size_t)jc1 * 128 + lane];

  while (rem >= 2) {
    // issue pair k+3
    int jn0 = __builtin_amdgcn_readfirstlane(rem > 6 ? csr[e + 6] : i);
    int jn1 = __builtin_amdgcn_readfirstlane(rem > 7 ? csr[e + 7] : i);
    uint2 un0 = rows[(size_t)jn0 * 128 + lane];
    uint2 un1 = rows[(size_t)jn1 * 128 + lane];
    // compute pair k (ua0, ua1)
    f32x2 x001 = bfpair(ua0.x), x023 = bfpair(ua0.y);
    f32x2 x101 = bfpair(ua1.x), x123 = bfpair(ua1.y);
    f32x2 q01 = x001 + xr01, q23 = x023 + xr23;
    f32x2 r01 = x101 + xr01, r23 = x123 + xr23;
    f32x2 g01 = __builtin_elementwise_max(q01, q01 * NEG);
    f32x2 g23 = __builtin_elementwise_max(q23, q23 * NEG);
    f32x2 k01 = __builtin_elementwise_max(r01, r01 * NEG);
    f32x2 k23 = __builtin_elementwise_max(r23, r23 * NEG);
    f32x2 s0v = g01 * a01 + g23 * a23;
    f32x2 s1v = k01 * a01 + k23 * a23;
    float p0 = s0v.x + s0v.y;
    float p1 = s1v.x + s1v.y;
    p0 += __shfl_xor(p0, 1, 8);
    p1 += __shfl_xor(p1, 1, 8);
    p0 += __shfl_xor(p0, 2, 8);
    p1 += __shfl_xor(p1, 2, 8);
    p0 += __shfl_xor(p0, 4, 8);
    p1 += __shfl_xor(p1, 4, 8);
    float mx = fmaxf(p0, p1);
    if (!__all(mx <= m + 8.f)) {        // defer-max (T13)
      float mn = fmaxf(m, mx);
      float sc = __expf(m - mn);
      O01 *= sc; O23 *= sc; ssum *= sc; m = mn;
    }
    float w0 = __expf(p0 - m), w1 = __expf(p1 - m);
    O01 += w0 * x001 + w1 * x101;
    O23 += w0 * x023 + w1 * x123;
    ssum += w0 + w1;
    // rotate queue
    ua0 = ub0; ua1 = ub1;
    ub0 = uc0; ub1 = uc1;
    uc0 = un0; uc1 = un1;
    e += 2; rem -= 2;
  }
  if (rem == 1) {
    f32x2 x001 = bfpair(ua0.x), x023 = bfpair(ua0.y);
    f32x2 q01 = x001 + xr01, q23 = x023 + xr23;
    f32x2 g01 = __builtin_elementwise_max(q01, q01 * NEG);
    f32x2 g23 = __builtin_elementwise_max(q23, q23 * NEG);
    f32x2 s0v = g01 * a01 + g23 * a23;
    float p0 = s0v.x + s0v.y;
    p0 += __shfl_xor(p0, 1, 8);
    p0 += __shfl_xor(p0, 2, 8);
    p0 += __shfl_xor(p0, 4, 8);
    if (!__all(p0 <= m + 8.f)) {
      float mn = fmaxf(m, p0);
      float sc = __expf(m - mn);
      O01 *= sc; O23 *= sc; ssum *= sc; m = mn;
    }
    float w0 = __expf(p0 - m);
    O01 += w0 * x001;
    O23 += w0 * x023;
    ssum += w0;
  }
  float inv = 1.f / (ssum + 1e-16f);
  float4 b4 = ((const float4*)bias)[lane];
  float h0 = O01.x * inv + b4.x;
  float h1 = O01.y * inv + b4.y;
  float h2 = O23.x * inv + b4.z;
  float h3 = O23.y * inv + b4.w;
  h0 = h0 > 0.f ? h0 : (__expf(h0) - 1.f);
  h1 = h1 > 0.f ? h1 : (__expf(h1) - 1.f);
  h2 = h2 > 0.f ? h2 : (__expf(h2) - 1.f);
  h3 = h3 > 0.f ? h3 : (__expf(h3) - 1.f);
  ushort4 o;
  o.x = f2bf(h0); o.y = f2bf(h1); o.z = f2bf(h2); o.w = f2bf(h3);
  ((ushort4*)(h + (size_t)i * 256))[lane] = o;
}

// ---------------- fused GATv2 layer 2 (bf16 in, depth-3 prefetch, defer-max) ----------------
__global__ __launch_bounds__(256) void gat2_kernel(const unsigned short* __restrict__ xlr2,
    const float* __restrict__ att, const float* __restrict__ b2,
    const int* __restrict__ offs, const int* __restrict__ csr,
    float* __restrict__ yout, int N) {
  int grp = threadIdx.x >> 4, c = threadIdx.x & 15;
  int i = blockIdx.x * 16 + grp;
  if (i >= N) return;
  float xli = bf2f(xlr2[(size_t)i * 32 + c]);
  float xri = bf2f(xlr2[(size_t)i * 32 + 16 + c]);
  float a = att[c];
  float v = xli + xri; v = fmaxf(v, NEG * v);
  float p = v * a;
#pragma unroll
  for (int o = 8; o >= 1; o >>= 1) p += __shfl_xor(p, o, 16);
  float m = p, ssum = 1.0f, O = xli;

  int e = offs[i], end = offs[i + 1];
  int rem = end - e;

  int ja0 = rem > 0 ? csr[e + 0] : i;
  int ja1 = rem > 1 ? csr[e + 1] : i;
  float xa0 = bf2f(xlr2[(size_t)ja0 * 32 + c]);
  float xa1 = bf2f(xlr2[(size_t)ja1 * 32 + c]);
  int jb0 = rem > 2 ? csr[e + 2] : i;
  int jb1 = rem > 3 ? csr[e + 3] : i;
  float xb0 = bf2f(xlr2[(size_t)jb0 * 32 + c]);
  float xb1 = bf2f(xlr2[(size_t)jb1 * 32 + c]);
  int jc0 = rem > 4 ? csr[e + 4] : i;
  int jc1 = rem > 5 ? csr[e + 5] : i;
  float xc0 = bf2f(xlr2[(size_t)jc0 * 32 + c]);
  float xc1 = bf2f(xlr2[(size_t)jc1 * 32 + c]);

  while (rem >= 2) {
    int jn0 = rem > 6 ? csr[e + 6] : i;
    int jn1 = rem > 7 ? csr[e + 7] : i;
    float xn0 = bf2f(xlr2[(size_t)jn0 * 32 + c]);
    float xn1 = bf2f(xlr2[(size_t)jn1 * 32 + c]);
    float q0 = xa0 + xri; q0 = fmaxf(q0, NEG * q0);
    float q1 = xa1 + xri; q1 = fmaxf(q1, NEG * q1);
    float p0 = q0 * a, p1 = q1 * a;
#pragma unroll
    for (int o = 8; o >= 1; o >>= 1) {
      p0 += __shfl_xor(p0, o, 16);
      p1 += __shfl_xor(p1, o, 16);
    }
    float mx = fmaxf(p0, p1);
    if (!__all(mx <= m + 8.f)) {
      float mn = fmaxf(m, mx);
      float sc = __expf(m - mn);
      O *= sc; ssum *= sc; m = mn;
    }
    float w0 = __expf(p0 - m), w1 = __expf(p1 - m);
    O += w0 * xa0 + w1 * xa1;
    ssum += w0 + w1;
    xa0 = xb0; xa1 = xb1;
    xb0 = xc0; xb1 = xc1;
    xc0 = xn0; xc1 = xn1;
    e += 2; rem -= 2;
  }
  if (rem == 1) {
    float q0 = xa0 + xri; q0 = fmaxf(q0, NEG * q0);
    float p0 = q0 * a;
#pragma unroll
    for (int o = 8; o >= 1; o >>= 1) p0 += __shfl_xor(p0, o, 16);
    if (!__all(p0 <= m + 8.f)) {
      float mn = fmaxf(m, p0);
      float sc = __expf(m - mn);
      O *= sc; ssum *= sc; m = mn;
    }
    float w0 = __expf(p0 - m);
    O += w0 * xa0;
    ssum += w0;
  }
  yout[(size_t)i * C2 + c] = O / (ssum + 1e-16f) + b2[c];
}

// ---------------- finalize ----------------
__global__ __launch_bounds__(256) void finalize_kernel(const float* __restrict__ y,
    const float* __restrict__ z, float* __restrict__ out, int N) {
  int grp = threadIdx.x >> 4, c = threadIdx.x & 15;
  int i = blockIdx.x * 16 + grp;
  if (i >= N) return;
  float yv = y[(size_t)i * C2 + c];
  float zv = z[(size_t)i * C2 + c];
  float my = yv;
#pragma unroll
  for (int o = 8; o >= 1; o >>= 1) my = fmaxf(my, __shfl_xor(my, o, 16));
  float sy = __expf(yv - my);
#pragma unroll
  for (int o = 8; o >= 1; o >>= 1) sy += __shfl_xor(sy, o, 16);
  float lpy = yv - my - __logf(sy);
  float mz = zv;
#pragma unroll
  for (int o = 8; o >= 1; o >>= 1) mz = fmaxf(mz, __shfl_xor(mz, o, 16));
  float sz = __expf(zv - mz);
#pragma unroll
  for (int o = 8; o >= 1; o >>= 1) sz += __shfl_xor(sz, o, 16);
  float lpz = zv - mz - __logf(sz);
  float dot = yv * zv, ny2 = yv * yv, nz2 = zv * zv;
#pragma unroll
  for (int o = 8; o >= 1; o >>= 1) {
    dot += __shfl_xor(dot, o, 16);
    ny2 += __shfl_xor(ny2, o, 16);
    nz2 += __shfl_xor(nz2, o, 16);
  }
  float ny = fmaxf(sqrtf(ny2), 1e-8f);
  float nz = fmaxf(sqrtf(nz2), 1e-8f);
  float cosv = dot / (ny * nz);
  size_t o1 = (size_t)N * C2;
  size_t o2 = o1 + N;
  size_t o3 = o2 + (size_t)N * C2;
  size_t o4 = o3 + (size_t)N * C2;
  size_t idx = (size_t)i * C2 + c;
  out[idx] = lpy;
  if (c == 0) out[o1 + i] = 1.0f - cosv;
  out[o2 + idx] = lpz;
  out[o3 + idx] = lpy;
  out[o4 + idx] = lpy;
}

extern "C" void kernel_launch(void* const* d_in, const int* in_sizes, int n_in,
                              void* d_out, int out_size, void* d_ws, size_t ws_size,
                              hipStream_t stream) {
  const float* x1   = (const float*)d_in[0];
  const int*   ei1  = (const int*)d_in[1];
  const float* x2   = (const float*)d_in[2];
  const int*   ei2  = (const int*)d_in[3];
  const float* W1l  = (const float*)d_in[4];
  const float* W1r  = (const float*)d_in[5];
  const float* att1 = (const float*)d_in[6];
  const float* b1   = (const float*)d_in[7];
  const float* W2l  = (const float*)d_in[8];
  const float* W2r  = (const float*)d_in[9];
  const float* att2 = (const float*)d_in[10];
  const float* b2   = (const float*)d_in[11];
  const int N = in_sizes[0] / FIN;
  const int E = in_sizes[1] / 2;
  float* out = (float*)d_out;

  char* w = (char*)d_ws;
  size_t off = 0;
  auto carve = [&](size_t bytes) -> void* {
    void* p = w + off;
    off += (bytes + 255) & ~(size_t)255;
    return p;
  };
  unsigned short* xlr_b = (unsigned short*)carve((size_t)N * 512 * 2);
  unsigned short* h     = (unsigned short*)carve((size_t)N * 256 * 2);
  unsigned short* Wt    = (unsigned short*)carve(512 * 256 * 2);
  unsigned short* Wt2   = (unsigned short*)carve(32 * 256 * 2);
  unsigned short* xlr2b = (unsigned short*)carve((size_t)N * 32 * 2);
  float* yb   = (float*)carve((size_t)N * 16 * 4);
  float* zb   = (float*)carve((size_t)N * 16 * 4);
  int* deg2 = (int*)carve((size_t)2 * N * 4);   // per-graph deg
  int* cnt2 = (int*)carve((size_t)2 * N * 4);   // per-graph cnt
  int* offs = (int*)carve((size_t)(N + 1) * 4);
  int* csr  = (int*)carve((size_t)E * 4);
  int* partials = (int*)carve(64 * 4);
  (void)ws_size; (void)n_in; (void)out_size;

  // one upfront memset spanning deg2..cnt2 (incl. carve padding)
  const size_t zero_bytes = (size_t)((char*)cnt2 - (char*)deg2) + (size_t)2 * N * 4;
  hipMemsetAsync(deg2, 0, zero_bytes, stream);

  const int NB = (N + 1023) / 1024;   // 49 for N=50000 (<=64 required)

  cvt_w_kernel<<<512, 256, 0, stream>>>(W1l, W1r, Wt);
  cvt_w2_kernel<<<32, 256, 0, stream>>>(W2l, W2r, Wt2);

  for (int g = 0; g < 2; g++) {
    const float* x  = g ? x2 : x1;
    const int*   ei = g ? ei2 : ei1;
    float* yout = g ? zb : yb;
    int* deg = deg2 + (size_t)g * N;
    int* cnt = cnt2 + (size_t)g * N;
    const int* srcp = ei;
    const int* dstp = ei + E;

    deg_kernel<<<(E + 255) / 256, 256, 0, stream>>>(dstp, deg, E);
    scan_part_kernel<<<NB, 1024, 0, stream>>>(deg, offs, partials, N);
    scan_fix_kernel<<<NB, 1024, 0, stream>>>(offs, partials, NB, N);
    fill_kernel<<<(E + 255) / 256, 256, 0, stream>>>(srcp, dstp, offs, cnt, csr, E);

    int RB = (N + 127) / 128;
    gemm_mfma_kernel<<<RB * 4, 256, 0, stream>>>(x, Wt, xlr_b, N);
    gat1_kernel<<<(N + 3) / 4, 256, 0, stream>>>(xlr_b, att1, b1, offs, csr, h, N);
    gemm2_mfma_kernel<<<(N + 255) / 256, 256, 0, stream>>>(h, Wt2, xlr2b, N);
    gat2_kernel<<<(N + 15) / 16, 256, 0, stream>>>(xlr2b, att2, b2, offs, csr, yout, N);
  }
  finalize_kernel<<<(N + 15) / 16, 256, 0, stream>>>(yb, zb, out, N);
}